// Round 13
// baseline (256.869 us; speedup 1.0000x reference)
//
#include <hip/hip_runtime.h>
#include <hip/hip_bf16.h>
#include <stdint.h>

// EncoderLayer: B=8 N=1024 D=512 H=8 Dh=64 FF=2048
#define B_   8
#define N_   1024
#define DM   512
#define H_   8
#define DFF  2048
#define ROWS (B_ * N_)          // 8192
#define QKV_LD (3 * DM)         // 1536
#define LOG2E 1.4426950408889634f
#define SCL  (0.125f * LOG2E)   // att scale 1/8 folded into exp2

typedef __bf16 bf16x8 __attribute__((ext_vector_type(8)));
typedef float  f32x4  __attribute__((ext_vector_type(4)));

__device__ __forceinline__ void gld_lds16(const void* g, void* l) {
  __builtin_amdgcn_global_load_lds((__attribute__((address_space(1))) void*)g,
                                   (__attribute__((address_space(3))) void*)l, 16, 0, 0);
}

__device__ __forceinline__ unsigned short bfb(float x) {
  __bf16 h = (__bf16)x;
  unsigned short u;
  __builtin_memcpy(&u, &h, 2);
  return u;
}

// ------- fused: prep (x_q=q+pos etc -> bf16) + all weight transposes --------
__global__ __launch_bounds__(256) void prep_and_wt(
    const float* __restrict__ q, const float* __restrict__ k,
    const float* __restrict__ v, const float* __restrict__ pos,
    __bf16* __restrict__ xq, __bf16* __restrict__ xk, __bf16* __restrict__ xv,
    const float* __restrict__ Wq, const float* __restrict__ Wk,
    const float* __restrict__ Wv, const float* __restrict__ Wo,
    const float* __restrict__ W1, const float* __restrict__ W2,
    __bf16* __restrict__ WqkvT, __bf16* __restrict__ WoT,
    __bf16* __restrict__ W1T, __bf16* __restrict__ W2T) {
  __shared__ float tl[32][33];
  if (blockIdx.x < 4096) {                    // ---- prep part
    int i = blockIdx.x * 256 + threadIdx.x;   // float4 group
    float4 pv = ((const float4*)pos)[i];
    float4 qv = ((const float4*)q)[i];
    float4 kv = ((const float4*)k)[i];
    float4 vv = ((const float4*)v)[i];
    ushort4 o;
    o.x = bfb(qv.x + pv.x); o.y = bfb(qv.y + pv.y); o.z = bfb(qv.z + pv.z); o.w = bfb(qv.w + pv.w);
    ((ushort4*)xq)[i] = o;
    o.x = bfb(kv.x + pv.x); o.y = bfb(kv.y + pv.y); o.z = bfb(kv.z + pv.z); o.w = bfb(kv.w + pv.w);
    ((ushort4*)xk)[i] = o;
    o.x = bfb(vv.x); o.y = bfb(vv.y); o.z = bfb(vv.z); o.w = bfb(vv.w);
    ((ushort4*)xv)[i] = o;
    return;
  }
  int idx = blockIdx.x - 4096;                // ---- weight transpose part
  const float* src; __bf16* dst; int K, N, t;
  if (idx < 768) {
    src = idx < 256 ? Wq : (idx < 512 ? Wk : Wv);
    dst = WqkvT + (size_t)(idx >> 8) * 512 * 512;
    K = 512; N = 512; t = idx & 255;
  } else if (idx < 1024) { src = Wo; dst = WoT;  K = 512;  N = 512;  t = idx - 768; }
  else if (idx < 2048)   { src = W1; dst = W1T;  K = 512;  N = 2048; t = idx - 1024; }
  else                   { src = W2; dst = W2T;  K = 2048; N = 512;  t = idx - 2048; }
  int tiles_n = N >> 5;
  int tn = t & (tiles_n - 1), tk = t / tiles_n;
  int n0 = tn * 32, k0 = tk * 32;
  int x = threadIdx.x & 31, y4 = threadIdx.x >> 5;
  #pragma unroll
  for (int j = y4; j < 32; j += 8) tl[j][x] = src[(size_t)(k0 + j) * N + n0 + x];
  __syncthreads();
  #pragma unroll
  for (int j = y4; j < 32; j += 8)
    dst[(size_t)(n0 + j) * K + k0 + x] = (__bf16)tl[x][j];
}

// ---------------- GEMM: C[M,N] = A[M,K] @ BT[N,K]^T + bias ------------------
// 2-phase pipelined: double-buffered LDS, counted vmcnt, raw barriers.
// EPI: 0 bf16 store, 1 bf16 relu store, 2 f32 store, 3 bf16 store + V-section
//      written transposed to Vtp (QKV gemm only).
template <int EPI, int BN>
__global__ __launch_bounds__(256, 2) void gemm_bt(
    const __bf16* __restrict__ A0, const __bf16* __restrict__ A1, const __bf16* __restrict__ A2,
    const __bf16* __restrict__ BT,
    const float* __restrict__ bias0, const float* __restrict__ bias1, const float* __restrict__ bias2,
    void* __restrict__ Cp, __bf16* __restrict__ Vtp, int M, int N, int K, int nsplit) {
  constexpr int NFR = BN / 32;          // B frags per wave
  constexpr int WCW = BN / 2;           // wave col width
  constexpr int BI  = BN / 32;          // B staging instrs per thread
  __shared__ __align__(16) __bf16 As[2][128 * 64];
  __shared__ __align__(16) __bf16 Bs[2][BN * 64];
  int tid = threadIdx.x, lane = tid & 63;
  int wave = tid >> 6;
  int wr = (wave >> 1) * 64, wc = (wave & 1) * WCW;

  int gx = N / BN;
  int nwg = gridDim.x;
  int cpx = nwg >> 3;
  int swz = (blockIdx.x & 7) * cpx + (blockIdx.x >> 3);
  int bx = swz % gx, by = swz / gx;
  int row0 = by << 7, col0 = bx * BN;

  int asel = col0 / nsplit;
  const __bf16* A = asel == 0 ? A0 : (asel == 1 ? A1 : A2);
  const float* bias = asel == 0 ? bias0 : (asel == 1 ? bias1 : bias2);

  f32x4 acc[4][NFR] = {};

#define GSTAGE(BUF, KT)                                                        \
  { _Pragma("unroll")                                                          \
    for (int i = 0; i < 4; ++i) {                                              \
      int t = i * 256 + tid;                                                   \
      int r = t >> 3, cS = (t & 7) ^ (r & 7);                                  \
      gld_lds16(A + (size_t)(row0 + r) * K + (KT) + cS * 8, As[BUF] + t * 8);  \
    }                                                                          \
    _Pragma("unroll")                                                          \
    for (int i = 0; i < BI; ++i) {                                             \
      int t = i * 256 + tid;                                                   \
      int r = t >> 3, cS = (t & 7) ^ (r & 7);                                  \
      gld_lds16(BT + (size_t)(col0 + r) * K + (KT) + cS * 8, Bs[BUF] + t * 8); \
    } }

#define GCOMP(BUF)                                                             \
  { const __bf16* Asc = As[BUF];                                               \
    const __bf16* Bsc = Bs[BUF];                                               \
    _Pragma("unroll")                                                          \
    for (int ks = 0; ks < 2; ++ks) {                                           \
      bf16x8 af[4], bfr[NFR];                                                  \
      _Pragma("unroll")                                                        \
      for (int m = 0; m < 4; ++m) {                                            \
        int r = wr + m * 16 + (lane & 15);                                     \
        int c = (ks * 4 + (lane >> 4)) ^ (r & 7);                              \
        af[m] = *(const bf16x8*)(Asc + r * 64 + c * 8);                        \
      }                                                                        \
      _Pragma("unroll")                                                        \
      for (int n = 0; n < NFR; ++n) {                                          \
        int r = wc + n * 16 + (lane & 15);                                     \
        int c = (ks * 4 + (lane >> 4)) ^ (r & 7);                              \
        bfr[n] = *(const bf16x8*)(Bsc + r * 64 + c * 8);                       \
      }                                                                        \
      _Pragma("unroll")                                                        \
      for (int m = 0; m < 4; ++m)                                              \
        _Pragma("unroll")                                                      \
        for (int n = 0; n < NFR; ++n)                                          \
          acc[m][n] = __builtin_amdgcn_mfma_f32_16x16x32_bf16(af[m], bfr[n], acc[m][n], 0, 0, 0); \
    } }

  GSTAGE(0, 0)
  int cur = 0;
  for (int kt = 64; kt < K; kt += 64) {
    GSTAGE(cur ^ 1, kt)
    if constexpr (BN == 128) asm volatile("s_waitcnt vmcnt(8)" ::: "memory");
    else                     asm volatile("s_waitcnt vmcnt(6)" ::: "memory");
    __builtin_amdgcn_s_barrier();
    __builtin_amdgcn_sched_barrier(0);
    GCOMP(cur)
    __builtin_amdgcn_s_barrier();     // protect buf[cur] from next stage
    cur ^= 1;
  }
  asm volatile("s_waitcnt vmcnt(0)" ::: "memory");
  __builtin_amdgcn_s_barrier();
  __builtin_amdgcn_sched_barrier(0);
  GCOMP(cur)
#undef GSTAGE
#undef GCOMP

  // epilogue: C row = (lane>>4)*4 + j, col = lane&15  (m89-verified layout)
  int rb = row0 + wr + ((lane >> 4) << 2);
  int cb = col0 + wc + (lane & 15);
  if (EPI == 3 && asel == 2) {
    // V panel: write transposed into Vt[(b*8+h)*64+d][n], packed 4 rows (8B)
    int bb = row0 >> 10;
    #pragma unroll
    for (int n = 0; n < NFR; ++n) {
      int c = cb + n * 16;                    // global col in [1024,1536)
      int d = c & 63, hh = (c >> 6) & 7;
      float bv = bias[c % nsplit];
      size_t vbase = ((size_t)((bb * 8 + hh) * 64 + d)) << 10;
      #pragma unroll
      for (int m = 0; m < 4; ++m) {
        int r0 = (rb + m * 16) & 1023;
        ushort4 pk;
        pk.x = bfb(acc[m][n][0] + bv);
        pk.y = bfb(acc[m][n][1] + bv);
        pk.z = bfb(acc[m][n][2] + bv);
        pk.w = bfb(acc[m][n][3] + bv);
        *(ushort4*)((__bf16*)Vtp + vbase + r0) = pk;
      }
    }
    return;
  }
  #pragma unroll
  for (int n = 0; n < NFR; ++n) {
    int c = cb + n * 16;
    float bv = bias[c % nsplit];
    #pragma unroll
    for (int m = 0; m < 4; ++m) {
      #pragma unroll
      for (int j = 0; j < 4; ++j) {
        int r = rb + m * 16 + j;
        float v = acc[m][n][j] + bv;
        if (EPI == 1) v = fmaxf(v, 0.f);
        if (EPI == 2) ((float*)Cp)[(size_t)r * N + c] = v;
        else          ((__bf16*)Cp)[(size_t)r * N + c] = (__bf16)v;
      }
    }
  }
}

// ---------------- fused attention v10: DIAGNOSTIC (2x duplicated grid) -------
// Same as v9 (R12) plus: (a) vmcnt LEDGER FIX — phase-top vmcnt(16) drains
// exactly KV(t), leaving all 16 rgw(t+1) loads in flight (v9's vmcnt(4)
// prematurely drained 12 of them); (b) plain loads for rgw (no nontemporal).
// DIAGNOSTIC: grid 2048 — blocks 1024..2047 duplicate 0..1023 (byte-identical
// writes, idempotent) to push the dispatch above the 155us fill dispatches so
// rocprof's top-5 finally shows attention's counters.
__global__ __launch_bounds__(256, 4) void attn_kernel(
    const __bf16* __restrict__ QKV, const __bf16* __restrict__ Vt,
    const float* __restrict__ rgw, __bf16* __restrict__ O) {
  __shared__ __align__(16) __bf16 QsPs[64 * 64];       // Qs (phase0) ∪ Ps
  __shared__ __align__(16) __bf16 Ks[2][64 * 64];
  __shared__ __align__(16) __bf16 Vs[2][64 * 64];

  int tid = threadIdx.x, lane = tid & 63, wave = tid >> 6;
  int swz2 = (blockIdx.x & 7) * (gridDim.x >> 3) + (blockIdx.x >> 3);
  int flat = swz2 & 1023;                                  // duplicate halves
  int qt = flat & 15, h = (flat >> 4) & 7, b = flat >> 7;
  int q0 = qt * 64;
  const int g = lane >> 4, u = lane & 15;

  // lane's q-row = q0 + wave*16 + u; att-col chunk starts at g*4
  const float* rgw_p = rgw +
      ((size_t)(b * H_ + h) * N_ + (size_t)(q0 + wave * 16 + u)) * N_ + g * 4;

#define STAGE_KV(BUF, KT)                                                      \
  {                                                                            \
    _Pragma("unroll")                                                          \
    for (int i = 0; i < 2; ++i) {                                              \
      int t = i * 256 + tid;                                                   \
      int r = t >> 3, cS = (t & 7) ^ (r & 7);                                  \
      gld_lds16(QKV + (size_t)(b * N_ + (KT) + r) * QKV_LD + DM + h * 64 + cS * 8, Ks[BUF] + t * 8); \
      gld_lds16(Vt + (size_t)((b * H_ + h) * 64 + r) * N_ + (KT) + cS * 8, Vs[BUF] + t * 8);         \
    }                                                                          \
  }
#define RPF(W, T)                                                              \
  {                                                                            \
    _Pragma("unroll")                                                          \
    for (int n = 0; n < 4; ++n)                                                \
      W[n] = *(const f32x4*)(rgw_p + (size_t)(T) * 64 + n * 16);               \
  }

  // ---- prologue: Q + KV[0] -> LDS; rgw tiles 0,1 -> registers ----
  #pragma unroll
  for (int i = 0; i < 2; ++i) {
    int t = i * 256 + tid;
    int r = t >> 3, cS = (t & 7) ^ (r & 7);
    gld_lds16(QKV + (size_t)(b * N_ + q0 + r) * QKV_LD + h * 64 + cS * 8, QsPs + t * 8);
  }
  STAGE_KV(0, 0)
  __builtin_amdgcn_sched_barrier(0);   // rgw loads AFTER Q/KV in the queue
  f32x4 wA[4], wB[4];
  RPF(wA, 0) RPF(wB, 1)
  __builtin_amdgcn_sched_barrier(0);

  float l = 0.f;
  f32x4 oacc[4] = {};
  bf16x8 qf[2];
  __bf16* pw = &QsPs[wave * 16 * 64];
  const int wrow = wave * 16 + u;
  union Pk { __bf16 h4[4]; unsigned long long q; };

#define PHASE(T16, WAITSTR, DOSTAGE, DORPF, WCON)                              \
  {                                                                            \
    asm volatile(WAITSTR ::: "memory");                                        \
    __builtin_amdgcn_s_barrier();                                              \
    if (DOSTAGE) { STAGE_KV(((T16) + 1) & 1, ((T16) + 1) * 64) }               \
    __builtin_amdgcn_sched_barrier(0);                                         \
    if ((T16) == 0) {                                                          \
      _Pragma("unroll")                                                        \
      for (int ks = 0; ks < 2; ++ks) {                                         \
        int c = (ks * 4 + g) ^ (wrow & 7);                                     \
        qf[ks] = *(const bf16x8*)(QsPs + wrow * 64 + c * 8);                   \
      }                                                                        \
    }                                                                          \
    f32x4 s[4] = {};                                                           \
    __builtin_amdgcn_s_setprio(1);                                             \
    _Pragma("unroll")                                                          \
    for (int ks = 0; ks < 2; ++ks) {                                           \
      _Pragma("unroll")                                                        \
      for (int n = 0; n < 4; ++n) {                                            \
        int r = n * 16 + u;                                                    \
        int c = (ks * 4 + g) ^ (r & 7);                                        \
        bf16x8 kf = *(const bf16x8*)(Ks[(T16) & 1] + r * 64 + c * 8);          \
        s[n] = __builtin_amdgcn_mfma_f32_16x16x32_bf16(kf, qf[ks], s[n], 0, 0, 0); \
      }                                                                        \
    }                                                                          \
    __builtin_amdgcn_s_setprio(0);                                             \
    if ((T16) == 0) __builtin_amdgcn_s_barrier();  /* all qf reads done before Ps writes (alias) */ \
    _Pragma("unroll")                                                          \
    for (int n = 0; n < 4; ++n) {                                              \
      Pk pk;                                                                   \
      _Pragma("unroll")                                                        \
      for (int j = 0; j < 4; ++j) {                                            \
        float pv = fmaxf(WCON[n][j], 1e-6f) * exp2f(s[n][j] * SCL);            \
        l += pv;                                                               \
        pk.h4[j] = (__bf16)pv;                                                 \
      }                                                                        \
      int bcol = 2 * n + (g >> 1);                                             \
      *(unsigned long long*)(pw + u * 64 + ((bcol ^ (u & 7)) << 3) + ((g & 1) << 2)) = pk.q; \
    }                                                                          \
    __builtin_amdgcn_sched_barrier(0);                                         \
    if (DORPF) { RPF(WCON, (T16) + 2) }                                        \
    __builtin_amdgcn_sched_barrier(0);                                         \
    __builtin_amdgcn_s_setprio(1);                                             \
    _Pragma("unroll")                                                          \
    for (int ks = 0; ks < 2; ++ks) {                                           \
      int cp = (ks * 4 + g) ^ (u & 7);                                         \
      bf16x8 pa = *(const bf16x8*)(pw + u * 64 + cp * 8);                      \
      _Pragma("unroll")                                                        \
      for (int n = 0; n < 4; ++n) {                                            \
        int r = n * 16 + u;                                                    \
        int c = (ks * 4 + g) ^ (r & 7);                                        \
        bf16x8 vb = *(const bf16x8*)(Vs[(T16) & 1] + r * 64 + c * 8);          \
        oacc[n] = __builtin_amdgcn_mfma_f32_16x16x32_bf16(pa, vb, oacc[n], 0, 0, 0); \
      }                                                                        \
    }                                                                          \
    __builtin_amdgcn_s_setprio(0);                                             \
  }

  // Ledger: at top of phase t, per-wave queue (old->new) = KV(t):4, rgw(t+1):16.
  // vmcnt(16) drains exactly KV(t); rgw(t+1) keeps its full slack.
  PHASE(0,  "s_waitcnt vmcnt(16)", 1, 1, wA)
  PHASE(1,  "s_waitcnt vmcnt(16)", 1, 1, wB)
  PHASE(2,  "s_waitcnt vmcnt(16)", 1, 1, wA)
  PHASE(3,  "s_waitcnt vmcnt(16)", 1, 1, wB)
  PHASE(4,  "s_waitcnt vmcnt(16)", 1, 1, wA)
  PHASE(5,  "s_waitcnt vmcnt(16)", 1, 1, wB)
  PHASE(6,  "s_waitcnt vmcnt(16)", 1, 1, wA)
  PHASE(7,  "s_waitcnt vmcnt(16)", 1, 1, wB)
  PHASE(8,  "s_waitcnt vmcnt(16)", 1, 1, wA)
  PHASE(9,  "s_waitcnt vmcnt(16)", 1, 1, wB)
  PHASE(10, "s_waitcnt vmcnt(16)", 1, 1, wA)
  PHASE(11, "s_waitcnt vmcnt(16)", 1, 1, wB)
  PHASE(12, "s_waitcnt vmcnt(16)", 1, 1, wA)
  PHASE(13, "s_waitcnt vmcnt(16)", 1, 1, wB)
  PHASE(14, "s_waitcnt vmcnt(16)", 1, 0, wA)
  PHASE(15, "s_waitcnt vmcnt(0)",  0, 0, wB)
#undef PHASE
#undef STAGE_KV
#undef RPF

  // row-sum: partials per lane (row u); sum across the 4 g-groups
  l += __shfl_xor(l, 16);
  l += __shfl_xor(l, 32);
  float linv[4];
  #pragma unroll
  for (int j = 0; j < 4; ++j)
    linv[j] = 1.f / __shfl(l, (lane & 48) | (g * 4 + j));

  int orow = b * N_ + q0 + wave * 16 + g * 4;
  int ocol = h * 64 + u;
  #pragma unroll
  for (int j = 0; j < 4; ++j)
    #pragma unroll
    for (int n = 0; n < 4; ++n)
      O[(size_t)(orow + j) * DM + ocol + n * 16] = (__bf16)(oacc[n][j] * linv[j]);
}

// ---------------- LayerNorm(x1 + x2); x2 optionally bf16 --------------------
template <int WRITE_BF, int X2BF>
__global__ __launch_bounds__(256) void ln_kernel(
    const float* __restrict__ x1, const void* __restrict__ x2v,
    const float* __restrict__ gw, const float* __restrict__ bw,
    float* __restrict__ outf, __bf16* __restrict__ outb) {
  __shared__ float red[8];
  int row = blockIdx.x, t = threadIdx.x;
  size_t base = (size_t)row * DM;
  float2 a = ((const float2*)(x1 + base))[t];
  float b0, b1;
  if (X2BF) {
    unsigned p = ((const unsigned*)x2v)[base / 2 + t];
    union { unsigned u; float f; } c0, c1;
    c0.u = p << 16; c1.u = p & 0xffff0000u;
    b0 = c0.f; b1 = c1.f;
  } else {
    float2 bb = ((const float2*)x2v)[base / 2 + t];
    b0 = bb.x; b1 = bb.y;
  }
  float v0 = a.x + b0, v1 = a.y + b1;
  float s = v0 + v1, s2 = v0 * v0 + v1 * v1;
  #pragma unroll
  for (int o = 32; o; o >>= 1) { s += __shfl_xor(s, o); s2 += __shfl_xor(s2, o); }
  int wave = t >> 6;
  if ((t & 63) == 0) { red[wave] = s; red[4 + wave] = s2; }
  __syncthreads();
  s = red[0] + red[1] + red[2] + red[3];
  s2 = red[4] + red[5] + red[6] + red[7];
  float mu = s * (1.f / DM);
  float var = s2 * (1.f / DM) - mu * mu;
  float rstd = rsqrtf(var + 1e-5f);
  float y0 = (v0 - mu) * rstd * gw[2 * t] + bw[2 * t];
  float y1 = (v1 - mu) * rstd * gw[2 * t + 1] + bw[2 * t + 1];
  float2 r; r.x = y0; r.y = y1;
  ((float2*)(outf + base))[t] = r;
  if (WRITE_BF) {
    ushort2 h; h.x = bfb(y0); h.y = bfb(y1);
    ((ushort2*)(outb + base))[t] = h;
  }
}

// ---------------- launch -----------------------------------------------------
extern "C" void kernel_launch(void* const* d_in, const int* in_sizes, int n_in,
                              void* d_out, int out_size, void* d_ws, size_t ws_size,
                              hipStream_t stream) {
  const float* queries = (const float*)d_in[0];
  const float* keys    = (const float*)d_in[1];
  const float* values  = (const float*)d_in[2];
  const float* rgw     = (const float*)d_in[3];
  const float* pos     = (const float*)d_in[4];
  const float* Wq = (const float*)d_in[5];
  const float* bq = (const float*)d_in[6];
  const float* Wk = (const float*)d_in[7];
  const float* bk = (const float*)d_in[8];
  const float* Wv = (const float*)d_in[9];
  const float* bv = (const float*)d_in[10];
  const float* Wo = (const float*)d_in[11];
  const float* bo = (const float*)d_in[12];
  const float* ln1g = (const float*)d_in[13];
  const float* ln1b = (const float*)d_in[14];
  const float* W1 = (const float*)d_in[15];
  const float* b1 = (const float*)d_in[16];
  const float* W2 = (const float*)d_in[17];
  const float* b2 = (const float*)d_in[18];
  const float* ln2g = (const float*)d_in[19];
  const float* ln2b = (const float*)d_in[20];
  float* out = (float*)d_out;

  char* ws = (char*)d_ws;
  const size_t SZX = (size_t)ROWS * DM * 2;        // 8 MB (bf16 8192x512)
  __bf16* Xq    = (__bf16*)(ws);
  __bf16* Xk    = (__bf16*)(ws + SZX);
  __bf16* Xv    = (__bf16*)(ws + 2 * SZX);
  __bf16* WqkvT = (__bf16*)(ws + 3 * SZX);                       // 1536x512
  __bf16* WoT   = (__bf16*)(ws + 3 * SZX + 1572864);             // 512x512
  __bf16* W1T   = (__bf16*)(ws + 3 * SZX + 2097152);             // 2048x512
  __bf16* W2T   = (__bf16*)(ws + 3 * SZX + 4194304);             // 512x2048
  __bf16* QKV   = (__bf16*)(ws + 3 * SZX + 6291456);             // 8192x1536
  __bf16* Vt    = (__bf16*)(ws + 3 * SZX + 6291456 + 3 * SZX);   // (B,H,64,N)
  __bf16* Oat   = (__bf16*)(ws + 3 * SZX + 6291456 + 4 * SZX);
  // aliases over dead regions:
  __bf16* attprojb = Xq;            // bf16 8192x512 over Xq (dead after QKV)
  __bf16* attoutb  = Xv;            // over Xv (dead after QKV GEMM)
  float*  attoutf  = (float*)QKV;   // f32 over QKV (dead after attention)
  __bf16* ff2b     = Vt;            // bf16 over Vt (dead after attention)
  __bf16* ff1      = (__bf16*)(ws + 3 * SZX + 6291456 + 5 * SZX); // 8192x2048

  prep_and_wt<<<4096 + 3072, 256, 0, stream>>>(
      queries, keys, values, pos, Xq, Xk, Xv,
      Wq, Wk, Wv, Wo, W1, W2, WqkvT, WoT, W1T, W2T);

  // QKV: C[8192,1536]; V panel goes straight to Vt (transposed)
  gemm_bt<3, 128><<<(ROWS / 128) * (QKV_LD / 128), 256, 0, stream>>>(
      Xq, Xk, Xv, WqkvT, bq, bk, bv, QKV, Vt, ROWS, QKV_LD, DM, DM);

  // DIAGNOSTIC: 2x duplicated grid so the dispatch exceeds the 155us fills
  // and surfaces in rocprof top-5 with full counters.
  attn_kernel<<<2 * B_ * H_ * (N_ / 64), 256, 0, stream>>>(QKV, Vt, rgw, Oat);

  // Wo -> bf16 attprojb; LN1(queries + attprojb) -> f32 + bf16
  gemm_bt<0, 64><<<(ROWS / 128) * (DM / 64), 256, 0, stream>>>(
      Oat, Oat, Oat, WoT, bo, bo, bo, attprojb, nullptr, ROWS, DM, DM, DM);

  ln_kernel<1, 1><<<ROWS, 256, 0, stream>>>(queries, attprojb, ln1g, ln1b, attoutf, attoutb);

  gemm_bt<1, 128><<<(ROWS / 128) * (DFF / 128), 256, 0, stream>>>(
      attoutb, attoutb, attoutb, W1T, b1, b1, b1, ff1, nullptr, ROWS, DFF, DM, DFF);

  // FF2 -> bf16 ff2b; LN2(attoutf + ff2b) -> out
  gemm_bt<0, 64><<<(ROWS / 128) * (DM / 64), 256, 0, stream>>>(
      ff1, ff1, ff1, W2T, b2, b2, b2, ff2b, nullptr, ROWS, DM, DFF, DM);

  ln_kernel<0, 1><<<ROWS, 256, 0, stream>>>(attoutf, ff2b, ln2g, ln2b, out, nullptr);
}

// Round 14
// 227.378 us; speedup vs baseline: 1.1297x; 1.1297x over previous
//
#include <hip/hip_runtime.h>
#include <hip/hip_bf16.h>
#include <stdint.h>

// EncoderLayer: B=8 N=1024 D=512 H=8 Dh=64 FF=2048
#define B_   8
#define N_   1024
#define DM   512
#define H_   8
#define DFF  2048
#define ROWS (B_ * N_)          // 8192
#define QKV_LD (3 * DM)         // 1536
#define LOG2E 1.4426950408889634f
#define SCL  (0.125f * LOG2E)   // att scale 1/8 folded into exp2

typedef __bf16 bf16x8 __attribute__((ext_vector_type(8)));
typedef float  f32x4  __attribute__((ext_vector_type(4)));

__device__ __forceinline__ void gld_lds16(const void* g, void* l) {
  __builtin_amdgcn_global_load_lds((__attribute__((address_space(1))) void*)g,
                                   (__attribute__((address_space(3))) void*)l, 16, 0, 0);
}

__device__ __forceinline__ unsigned short bfb(float x) {
  __bf16 h = (__bf16)x;
  unsigned short u;
  __builtin_memcpy(&u, &h, 2);
  return u;
}

// ------- fused: prep (x_q=q+pos etc -> bf16) + all weight transposes --------
__global__ __launch_bounds__(256) void prep_and_wt(
    const float* __restrict__ q, const float* __restrict__ k,
    const float* __restrict__ v, const float* __restrict__ pos,
    __bf16* __restrict__ xq, __bf16* __restrict__ xk, __bf16* __restrict__ xv,
    const float* __restrict__ Wq, const float* __restrict__ Wk,
    const float* __restrict__ Wv, const float* __restrict__ Wo,
    const float* __restrict__ W1, const float* __restrict__ W2,
    __bf16* __restrict__ WqkvT, __bf16* __restrict__ WoT,
    __bf16* __restrict__ W1T, __bf16* __restrict__ W2T) {
  __shared__ float tl[32][33];
  if (blockIdx.x < 4096) {                    // ---- prep part
    int i = blockIdx.x * 256 + threadIdx.x;   // float4 group
    float4 pv = ((const float4*)pos)[i];
    float4 qv = ((const float4*)q)[i];
    float4 kv = ((const float4*)k)[i];
    float4 vv = ((const float4*)v)[i];
    ushort4 o;
    o.x = bfb(qv.x + pv.x); o.y = bfb(qv.y + pv.y); o.z = bfb(qv.z + pv.z); o.w = bfb(qv.w + pv.w);
    ((ushort4*)xq)[i] = o;
    o.x = bfb(kv.x + pv.x); o.y = bfb(kv.y + pv.y); o.z = bfb(kv.z + pv.z); o.w = bfb(kv.w + pv.w);
    ((ushort4*)xk)[i] = o;
    o.x = bfb(vv.x); o.y = bfb(vv.y); o.z = bfb(vv.z); o.w = bfb(vv.w);
    ((ushort4*)xv)[i] = o;
    return;
  }
  int idx = blockIdx.x - 4096;                // ---- weight transpose part
  const float* src; __bf16* dst; int K, N, t;
  if (idx < 768) {
    src = idx < 256 ? Wq : (idx < 512 ? Wk : Wv);
    dst = WqkvT + (size_t)(idx >> 8) * 512 * 512;
    K = 512; N = 512; t = idx & 255;
  } else if (idx < 1024) { src = Wo; dst = WoT;  K = 512;  N = 512;  t = idx - 768; }
  else if (idx < 2048)   { src = W1; dst = W1T;  K = 512;  N = 2048; t = idx - 1024; }
  else                   { src = W2; dst = W2T;  K = 2048; N = 512;  t = idx - 2048; }
  int tiles_n = N >> 5;
  int tn = t & (tiles_n - 1), tk = t / tiles_n;
  int n0 = tn * 32, k0 = tk * 32;
  int x = threadIdx.x & 31, y4 = threadIdx.x >> 5;
  #pragma unroll
  for (int j = y4; j < 32; j += 8) tl[j][x] = src[(size_t)(k0 + j) * N + n0 + x];
  __syncthreads();
  #pragma unroll
  for (int j = y4; j < 32; j += 8)
    dst[(size_t)(n0 + j) * K + k0 + x] = (__bf16)tl[x][j];
}

// ---------------- GEMM: C[M,N] = A[M,K] @ BT[N,K]^T + bias ------------------
// 2-phase pipelined: double-buffered LDS, counted vmcnt, raw barriers.
// EPI: 0 bf16 store, 1 bf16 relu store, 2 f32 store, 3 bf16 store + V-section
//      written transposed to Vtp (QKV gemm only).
template <int EPI, int BN>
__global__ __launch_bounds__(256, 2) void gemm_bt(
    const __bf16* __restrict__ A0, const __bf16* __restrict__ A1, const __bf16* __restrict__ A2,
    const __bf16* __restrict__ BT,
    const float* __restrict__ bias0, const float* __restrict__ bias1, const float* __restrict__ bias2,
    void* __restrict__ Cp, __bf16* __restrict__ Vtp, int M, int N, int K, int nsplit) {
  constexpr int NFR = BN / 32;          // B frags per wave
  constexpr int WCW = BN / 2;           // wave col width
  constexpr int BI  = BN / 32;          // B staging instrs per thread
  __shared__ __align__(16) __bf16 As[2][128 * 64];
  __shared__ __align__(16) __bf16 Bs[2][BN * 64];
  int tid = threadIdx.x, lane = tid & 63;
  int wave = tid >> 6;
  int wr = (wave >> 1) * 64, wc = (wave & 1) * WCW;

  int gx = N / BN;
  int nwg = gridDim.x;
  int cpx = nwg >> 3;
  int swz = (blockIdx.x & 7) * cpx + (blockIdx.x >> 3);
  int bx = swz % gx, by = swz / gx;
  int row0 = by << 7, col0 = bx * BN;

  int asel = col0 / nsplit;
  const __bf16* A = asel == 0 ? A0 : (asel == 1 ? A1 : A2);
  const float* bias = asel == 0 ? bias0 : (asel == 1 ? bias1 : bias2);

  f32x4 acc[4][NFR] = {};

#define GSTAGE(BUF, KT)                                                        \
  { _Pragma("unroll")                                                          \
    for (int i = 0; i < 4; ++i) {                                              \
      int t = i * 256 + tid;                                                   \
      int r = t >> 3, cS = (t & 7) ^ (r & 7);                                  \
      gld_lds16(A + (size_t)(row0 + r) * K + (KT) + cS * 8, As[BUF] + t * 8);  \
    }                                                                          \
    _Pragma("unroll")                                                          \
    for (int i = 0; i < BI; ++i) {                                             \
      int t = i * 256 + tid;                                                   \
      int r = t >> 3, cS = (t & 7) ^ (r & 7);                                  \
      gld_lds16(BT + (size_t)(col0 + r) * K + (KT) + cS * 8, Bs[BUF] + t * 8); \
    } }

#define GCOMP(BUF)                                                             \
  { const __bf16* Asc = As[BUF];                                               \
    const __bf16* Bsc = Bs[BUF];                                               \
    _Pragma("unroll")                                                          \
    for (int ks = 0; ks < 2; ++ks) {                                           \
      bf16x8 af[4], bfr[NFR];                                                  \
      _Pragma("unroll")                                                        \
      for (int m = 0; m < 4; ++m) {                                            \
        int r = wr + m * 16 + (lane & 15);                                     \
        int c = (ks * 4 + (lane >> 4)) ^ (r & 7);                              \
        af[m] = *(const bf16x8*)(Asc + r * 64 + c * 8);                        \
      }                                                                        \
      _Pragma("unroll")                                                        \
      for (int n = 0; n < NFR; ++n) {                                          \
        int r = wc + n * 16 + (lane & 15);                                     \
        int c = (ks * 4 + (lane >> 4)) ^ (r & 7);                              \
        bfr[n] = *(const bf16x8*)(Bsc + r * 64 + c * 8);                       \
      }                                                                        \
      _Pragma("unroll")                                                        \
      for (int m = 0; m < 4; ++m)                                              \
        _Pragma("unroll")                                                      \
        for (int n = 0; n < NFR; ++n)                                          \
          acc[m][n] = __builtin_amdgcn_mfma_f32_16x16x32_bf16(af[m], bfr[n], acc[m][n], 0, 0, 0); \
    } }

  GSTAGE(0, 0)
  int cur = 0;
  for (int kt = 64; kt < K; kt += 64) {
    GSTAGE(cur ^ 1, kt)
    if constexpr (BN == 128) asm volatile("s_waitcnt vmcnt(8)" ::: "memory");
    else                     asm volatile("s_waitcnt vmcnt(6)" ::: "memory");
    __builtin_amdgcn_s_barrier();
    __builtin_amdgcn_sched_barrier(0);
    GCOMP(cur)
    __builtin_amdgcn_s_barrier();     // protect buf[cur] from next stage
    cur ^= 1;
  }
  asm volatile("s_waitcnt vmcnt(0)" ::: "memory");
  __builtin_amdgcn_s_barrier();
  __builtin_amdgcn_sched_barrier(0);
  GCOMP(cur)
#undef GSTAGE
#undef GCOMP

  // epilogue: C row = (lane>>4)*4 + j, col = lane&15  (m89-verified layout)
  int rb = row0 + wr + ((lane >> 4) << 2);
  int cb = col0 + wc + (lane & 15);
  if (EPI == 3 && asel == 2) {
    // V panel: write transposed into Vt[(b*8+h)*64+d][n], packed 4 rows (8B)
    int bb = row0 >> 10;
    #pragma unroll
    for (int n = 0; n < NFR; ++n) {
      int c = cb + n * 16;                    // global col in [1024,1536)
      int d = c & 63, hh = (c >> 6) & 7;
      float bv = bias[c % nsplit];
      size_t vbase = ((size_t)((bb * 8 + hh) * 64 + d)) << 10;
      #pragma unroll
      for (int m = 0; m < 4; ++m) {
        int r0 = (rb + m * 16) & 1023;
        ushort4 pk;
        pk.x = bfb(acc[m][n][0] + bv);
        pk.y = bfb(acc[m][n][1] + bv);
        pk.z = bfb(acc[m][n][2] + bv);
        pk.w = bfb(acc[m][n][3] + bv);
        *(ushort4*)((__bf16*)Vtp + vbase + r0) = pk;
      }
    }
    return;
  }
  #pragma unroll
  for (int n = 0; n < NFR; ++n) {
    int c = cb + n * 16;
    float bv = bias[c % nsplit];
    #pragma unroll
    for (int m = 0; m < 4; ++m) {
      #pragma unroll
      for (int j = 0; j < 4; ++j) {
        int r = rb + m * 16 + j;
        float v = acc[m][n][j] + bv;
        if (EPI == 1) v = fmaxf(v, 0.f);
        if (EPI == 2) ((float*)Cp)[(size_t)r * N + c] = v;
        else          ((__bf16*)Cp)[(size_t)r * N + c] = (__bf16)v;
      }
    }
  }
}

// ---------------- fused attention v11: 512-B DRAM bursts for rgw -------------
// softmax(log(clip(w)) + s) == normalize(clip(w) * exp(s)) exactly.
// SWAPPED QK^T: mfma(K,Q) -> lane owns q-row u, att-cols n*16+g*4+{0..3}.
// DRAM-burst hypothesis (from R13: L3-warm pass = 47us ~= floor, HBM-cold =
// ~87us at 3.3TB/s): all prior variants read rgw rows in 256-B pieces ->
// activate-limited DRAM. This version prefetches rgw in PAIRS of k-tiles:
// 8 back-to-back dwordx4 covering 128 consecutive cols per row = 512-B
// bursts. wE/wO pair double-buffer (64 VGPR). Instruction-count ledger
// (KV=4, rgw=8 per wave): odd-phase tops vmcnt(8) keep rgw in flight; even
// tops vmcnt(0) (rgw is 2 phases old -> landed, wait~0). Qs aliased over Ps
// (extra barrier after phase-0 QK). launch_bounds(256,3): ~134 VGPR, no
// forced spill (3 vs 4 blocks/CU measured neutral R9/R12).
__global__ __launch_bounds__(256, 3) void attn_kernel(
    const __bf16* __restrict__ QKV, const __bf16* __restrict__ Vt,
    const float* __restrict__ rgw, __bf16* __restrict__ O) {
  __shared__ __align__(16) __bf16 QsPs[64 * 64];       // Qs (phase0) ∪ Ps
  __shared__ __align__(16) __bf16 Ks[2][64 * 64];
  __shared__ __align__(16) __bf16 Vs[2][64 * 64];

  int tid = threadIdx.x, lane = tid & 63, wave = tid >> 6;
  int flat = (blockIdx.x & 7) * 128 + (blockIdx.x >> 3);   // bijective XCD swz
  int qt = flat & 15, h = (flat >> 4) & 7, b = flat >> 7;
  int q0 = qt * 64;
  const int g = lane >> 4, u = lane & 15;

  // lane's q-row = q0 + wave*16 + u; att-col chunk starts at g*4
  const float* rgw_p = rgw +
      ((size_t)(b * H_ + h) * N_ + (size_t)(q0 + wave * 16 + u)) * N_ + g * 4;

#define STAGE_KV(BUF, KT)                                                      \
  {                                                                            \
    _Pragma("unroll")                                                          \
    for (int i = 0; i < 2; ++i) {                                              \
      int t = i * 256 + tid;                                                   \
      int r = t >> 3, cS = (t & 7) ^ (r & 7);                                  \
      gld_lds16(QKV + (size_t)(b * N_ + (KT) + r) * QKV_LD + DM + h * 64 + cS * 8, Ks[BUF] + t * 8); \
      gld_lds16(Vt + (size_t)((b * H_ + h) * 64 + r) * N_ + (KT) + cS * 8, Vs[BUF] + t * 8);         \
    }                                                                          \
  }
// fetch PAIR of k-tiles (128 cols = 512 B/row) in 8 consecutive dwordx4
#define RPF8(W, PQ)                                                            \
  {                                                                            \
    _Pragma("unroll")                                                          \
    for (int n = 0; n < 8; ++n)                                                \
      W[n] = *(const f32x4*)(rgw_p + (size_t)(PQ) * 128 + n * 16);             \
  }

  // ---- prologue: Q + KV[0] -> LDS; rgw pair 0 -> wE ----
  #pragma unroll
  for (int i = 0; i < 2; ++i) {
    int t = i * 256 + tid;
    int r = t >> 3, cS = (t & 7) ^ (r & 7);
    gld_lds16(QKV + (size_t)(b * N_ + q0 + r) * QKV_LD + h * 64 + cS * 8, QsPs + t * 8);
  }
  STAGE_KV(0, 0)
  __builtin_amdgcn_sched_barrier(0);   // rgw loads AFTER Q/KV in the queue
  f32x4 wE[8], wO[8];
  RPF8(wE, 0)
  __builtin_amdgcn_sched_barrier(0);

  float l = 0.f;
  f32x4 oacc[4] = {};
  bf16x8 qf[2];
  __bf16* pw = &QsPs[wave * 16 * 64];
  const int wrow = wave * 16 + u;
  union Pk { __bf16 h4[4]; unsigned long long q; };

#define PHASE(T16, WAITSTR, DOSTAGE, DORPF, WCON, WOFF, WPF, PQ)               \
  {                                                                            \
    asm volatile(WAITSTR ::: "memory");                                        \
    __builtin_amdgcn_s_barrier();                                              \
    if (DOSTAGE) { STAGE_KV(((T16) + 1) & 1, ((T16) + 1) * 64) }               \
    __builtin_amdgcn_sched_barrier(0);                                         \
    if (DORPF) { RPF8(WPF, PQ) }                                               \
    __builtin_amdgcn_sched_barrier(0);                                         \
    if ((T16) == 0) {                                                          \
      _Pragma("unroll")                                                        \
      for (int ks = 0; ks < 2; ++ks) {                                         \
        int c = (ks * 4 + g) ^ (wrow & 7);                                     \
        qf[ks] = *(const bf16x8*)(QsPs + wrow * 64 + c * 8);                   \
      }                                                                        \
    }                                                                          \
    f32x4 s[4] = {};                                                           \
    __builtin_amdgcn_s_setprio(1);                                             \
    _Pragma("unroll")                                                          \
    for (int ks = 0; ks < 2; ++ks) {                                           \
      _Pragma("unroll")                                                        \
      for (int n = 0; n < 4; ++n) {                                            \
        int r = n * 16 + u;                                                    \
        int c = (ks * 4 + g) ^ (r & 7);                                        \
        bf16x8 kf = *(const bf16x8*)(Ks[(T16) & 1] + r * 64 + c * 8);          \
        s[n] = __builtin_amdgcn_mfma_f32_16x16x32_bf16(kf, qf[ks], s[n], 0, 0, 0); \
      }                                                                        \
    }                                                                          \
    __builtin_amdgcn_s_setprio(0);                                             \
    if ((T16) == 0) __builtin_amdgcn_s_barrier();  /* qf reads done before Ps writes (alias) */ \
    _Pragma("unroll")                                                          \
    for (int n = 0; n < 4; ++n) {                                              \
      Pk pk;                                                                   \
      _Pragma("unroll")                                                        \
      for (int j = 0; j < 4; ++j) {                                            \
        float pv = fmaxf(WCON[(WOFF) + n][j], 1e-6f) * exp2f(s[n][j] * SCL);   \
        l += pv;                                                               \
        pk.h4[j] = (__bf16)pv;                                                 \
      }                                                                        \
      int bcol = 2 * n + (g >> 1);                                             \
      *(unsigned long long*)(pw + u * 64 + ((bcol ^ (u & 7)) << 3) + ((g & 1) << 2)) = pk.q; \
    }                                                                          \
    __builtin_amdgcn_s_setprio(1);                                             \
    _Pragma("unroll")                                                          \
    for (int ks = 0; ks < 2; ++ks) {                                           \
      int cp = (ks * 4 + g) ^ (u & 7);                                         \
      bf16x8 pa = *(const bf16x8*)(pw + u * 64 + cp * 8);                      \
      _Pragma("unroll")                                                        \
      for (int n = 0; n < 4; ++n) {                                            \
        int r = n * 16 + u;                                                    \
        int c = (ks * 4 + g) ^ (r & 7);                                        \
        bf16x8 vb = *(const bf16x8*)(Vs[(T16) & 1] + r * 64 + c * 8);          \
        oacc[n] = __builtin_amdgcn_mfma_f32_16x16x32_bf16(pa, vb, oacc[n], 0, 0, 0); \
      }                                                                        \
    }                                                                          \
    __builtin_amdgcn_s_setprio(0);                                             \
  }

  // Pair schedule: pair q covers phases 2q,2q+1 (cols 128q..128q+127).
  // pair0 -> wE (prologue); pair q+1 fetched at even phase 2q into the
  // buffer freed at 2q-1. Ledger/wave: KV=4 instrs, rgw=8 instrs.
  // Odd tops: [KV(t):4, rgw:8] -> vmcnt(8). Even tops: rgw is oldest and
  // needed now -> vmcnt(0) (landed; 2 phases slack).
  PHASE(0,  "s_waitcnt vmcnt(0)", 1, 1, wE, 0, wO, 1)
  PHASE(1,  "s_waitcnt vmcnt(8)", 1, 0, wE, 4, wO, 0)
  PHASE(2,  "s_waitcnt vmcnt(0)", 1, 1, wO, 0, wE, 2)
  PHASE(3,  "s_waitcnt vmcnt(8)", 1, 0, wO, 4, wE, 0)
  PHASE(4,  "s_waitcnt vmcnt(0)", 1, 1, wE, 0, wO, 3)
  PHASE(5,  "s_waitcnt vmcnt(8)", 1, 0, wE, 4, wO, 0)
  PHASE(6,  "s_waitcnt vmcnt(0)", 1, 1, wO, 0, wE, 4)
  PHASE(7,  "s_waitcnt vmcnt(8)", 1, 0, wO, 4, wE, 0)
  PHASE(8,  "s_waitcnt vmcnt(0)", 1, 1, wE, 0, wO, 5)
  PHASE(9,  "s_waitcnt vmcnt(8)", 1, 0, wE, 4, wO, 0)
  PHASE(10, "s_waitcnt vmcnt(0)", 1, 1, wO, 0, wE, 6)
  PHASE(11, "s_waitcnt vmcnt(8)", 1, 0, wO, 4, wE, 0)
  PHASE(12, "s_waitcnt vmcnt(0)", 1, 1, wE, 0, wO, 7)
  PHASE(13, "s_waitcnt vmcnt(8)", 1, 0, wE, 4, wO, 0)
  PHASE(14, "s_waitcnt vmcnt(0)", 1, 0, wO, 0, wE, 0)
  PHASE(15, "s_waitcnt vmcnt(0)", 0, 0, wO, 4, wE, 0)
#undef PHASE
#undef STAGE_KV
#undef RPF8

  // row-sum: partials per lane (row u); sum across the 4 g-groups
  l += __shfl_xor(l, 16);
  l += __shfl_xor(l, 32);
  float linv[4];
  #pragma unroll
  for (int j = 0; j < 4; ++j)
    linv[j] = 1.f / __shfl(l, (lane & 48) | (g * 4 + j));

  int orow = b * N_ + q0 + wave * 16 + g * 4;
  int ocol = h * 64 + u;
  #pragma unroll
  for (int j = 0; j < 4; ++j)
    #pragma unroll
    for (int n = 0; n < 4; ++n)
      O[(size_t)(orow + j) * DM + ocol + n * 16] = (__bf16)(oacc[n][j] * linv[j]);
}

// ---------------- LayerNorm(x1 + x2); x2 optionally bf16 --------------------
template <int WRITE_BF, int X2BF>
__global__ __launch_bounds__(256) void ln_kernel(
    const float* __restrict__ x1, const void* __restrict__ x2v,
    const float* __restrict__ gw, const float* __restrict__ bw,
    float* __restrict__ outf, __bf16* __restrict__ outb) {
  __shared__ float red[8];
  int row = blockIdx.x, t = threadIdx.x;
  size_t base = (size_t)row * DM;
  float2 a = ((const float2*)(x1 + base))[t];
  float b0, b1;
  if (X2BF) {
    unsigned p = ((const unsigned*)x2v)[base / 2 + t];
    union { unsigned u; float f; } c0, c1;
    c0.u = p << 16; c1.u = p & 0xffff0000u;
    b0 = c0.f; b1 = c1.f;
  } else {
    float2 bb = ((const float2*)x2v)[base / 2 + t];
    b0 = bb.x; b1 = bb.y;
  }
  float v0 = a.x + b0, v1 = a.y + b1;
  float s = v0 + v1, s2 = v0 * v0 + v1 * v1;
  #pragma unroll
  for (int o = 32; o; o >>= 1) { s += __shfl_xor(s, o); s2 += __shfl_xor(s2, o); }
  int wave = t >> 6;
  if ((t & 63) == 0) { red[wave] = s; red[4 + wave] = s2; }
  __syncthreads();
  s = red[0] + red[1] + red[2] + red[3];
  s2 = red[4] + red[5] + red[6] + red[7];
  float mu = s * (1.f / DM);
  float var = s2 * (1.f / DM) - mu * mu;
  float rstd = rsqrtf(var + 1e-5f);
  float y0 = (v0 - mu) * rstd * gw[2 * t] + bw[2 * t];
  float y1 = (v1 - mu) * rstd * gw[2 * t + 1] + bw[2 * t + 1];
  float2 r; r.x = y0; r.y = y1;
  ((float2*)(outf + base))[t] = r;
  if (WRITE_BF) {
    ushort2 h; h.x = bfb(y0); h.y = bfb(y1);
    ((ushort2*)(outb + base))[t] = h;
  }
}

// ---------------- launch -----------------------------------------------------
extern "C" void kernel_launch(void* const* d_in, const int* in_sizes, int n_in,
                              void* d_out, int out_size, void* d_ws, size_t ws_size,
                              hipStream_t stream) {
  const float* queries = (const float*)d_in[0];
  const float* keys    = (const float*)d_in[1];
  const float* values  = (const float*)d_in[2];
  const float* rgw     = (const float*)d_in[3];
  const float* pos     = (const float*)d_in[4];
  const float* Wq = (const float*)d_in[5];
  const float* bq = (const float*)d_in[6];
  const float* Wk = (const float*)d_in[7];
  const float* bk = (const float*)d_in[8];
  const float* Wv = (const float*)d_in[9];
  const float* bv = (const float*)d_in[10];
  const float* Wo = (const float*)d_in[11];
  const float* bo = (const float*)d_in[12];
  const float* ln1g = (const float*)d_in[13];
  const float* ln1b = (const float*)d_in[14];
  const float* W1 = (const float*)d_in[15];
  const float* b1 = (const float*)d_in[16];
  const float* W2 = (const float*)d_in[17];
  const float* b2 = (const float*)d_in[18];
  const float* ln2g = (const float*)d_in[19];
  const float* ln2b = (const float*)d_in[20];
  float* out = (float*)d_out;

  char* ws = (char*)d_ws;
  const size_t SZX = (size_t)ROWS * DM * 2;        // 8 MB (bf16 8192x512)
  __bf16* Xq    = (__bf16*)(ws);
  __bf16* Xk    = (__bf16*)(ws + SZX);
  __bf16* Xv    = (__bf16*)(ws + 2 * SZX);
  __bf16* WqkvT = (__bf16*)(ws + 3 * SZX);                       // 1536x512
  __bf16* WoT   = (__bf16*)(ws + 3 * SZX + 1572864);             // 512x512
  __bf16* W1T   = (__bf16*)(ws + 3 * SZX + 2097152);             // 2048x512
  __bf16* W2T   = (__bf16*)(ws + 3 * SZX + 4194304);             // 512x2048
  __bf16* QKV   = (__bf16*)(ws + 3 * SZX + 6291456);             // 8192x1536
  __bf16* Vt    = (__bf16*)(ws + 3 * SZX + 6291456 + 3 * SZX);   // (B,H,64,N)
  __bf16* Oat   = (__bf16*)(ws + 3 * SZX + 6291456 + 4 * SZX);
  // aliases over dead regions:
  __bf16* attprojb = Xq;            // bf16 8192x512 over Xq (dead after QKV)
  __bf16* attoutb  = Xv;            // over Xv (dead after QKV GEMM)
  float*  attoutf  = (float*)QKV;   // f32 over QKV (dead after attention)
  __bf16* ff2b     = Vt;            // bf16 over Vt (dead after attention)
  __bf16* ff1      = (__bf16*)(ws + 3 * SZX + 6291456 + 5 * SZX); // 8192x2048

  prep_and_wt<<<4096 + 3072, 256, 0, stream>>>(
      queries, keys, values, pos, Xq, Xk, Xv,
      Wq, Wk, Wv, Wo, W1, W2, WqkvT, WoT, W1T, W2T);

  // QKV: C[8192,1536]; V panel goes straight to Vt (transposed)
  gemm_bt<3, 128><<<(ROWS / 128) * (QKV_LD / 128), 256, 0, stream>>>(
      Xq, Xk, Xv, WqkvT, bq, bk, bv, QKV, Vt, ROWS, QKV_LD, DM, DM);

  attn_kernel<<<B_ * H_ * (N_ / 64), 256, 0, stream>>>(QKV, Vt, rgw, Oat);

  // Wo -> bf16 attprojb; LN1(queries + attprojb) -> f32 + bf16
  gemm_bt<0, 64><<<(ROWS / 128) * (DM / 64), 256, 0, stream>>>(
      Oat, Oat, Oat, WoT, bo, bo, bo, attprojb, nullptr, ROWS, DM, DM, DM);

  ln_kernel<1, 1><<<ROWS, 256, 0, stream>>>(queries, attprojb, ln1g, ln1b, attoutf, attoutb);

  gemm_bt<1, 128><<<(ROWS / 128) * (DFF / 128), 256, 0, stream>>>(
      attoutb, attoutb, attoutb, W1T, b1, b1, b1, ff1, nullptr, ROWS, DFF, DM, DFF);

  // FF2 -> bf16 ff2b; LN2(attoutf + ff2b) -> out
  gemm_bt<0, 64><<<(ROWS / 128) * (DM / 64), 256, 0, stream>>>(
      ff1, ff1, ff1, W2T, b2, b2, b2, ff2b, nullptr, ROWS, DM, DFF, DM);

  ln_kernel<0, 1><<<ROWS, 256, 0, stream>>>(attoutf, ff2b, ln2g, ln2b, out, nullptr);
}

// Round 15
// 225.398 us; speedup vs baseline: 1.1396x; 1.0088x over previous
//
#include <hip/hip_runtime.h>
#include <hip/hip_bf16.h>
#include <stdint.h>

// EncoderLayer: B=8 N=1024 D=512 H=8 Dh=64 FF=2048
#define B_   8
#define N_   1024
#define DM   512
#define H_   8
#define DFF  2048
#define ROWS (B_ * N_)          // 8192
#define QKV_LD (3 * DM)         // 1536
#define LOG2E 1.4426950408889634f
#define SCL  (0.125f * LOG2E)   // att scale 1/8 folded into exp2

typedef __bf16 bf16x8 __attribute__((ext_vector_type(8)));
typedef float  f32x4  __attribute__((ext_vector_type(4)));

__device__ __forceinline__ void gld_lds16(const void* g, void* l) {
  __builtin_amdgcn_global_load_lds((__attribute__((address_space(1))) void*)g,
                                   (__attribute__((address_space(3))) void*)l, 16, 0, 0);
}

__device__ __forceinline__ unsigned short bfb(float x) {
  __bf16 h = (__bf16)x;
  unsigned short u;
  __builtin_memcpy(&u, &h, 2);
  return u;
}

// ------- fused: prep (x_q=q+pos etc -> bf16) + all weight transposes --------
__global__ __launch_bounds__(256) void prep_and_wt(
    const float* __restrict__ q, const float* __restrict__ k,
    const float* __restrict__ v, const float* __restrict__ pos,
    __bf16* __restrict__ xq, __bf16* __restrict__ xk, __bf16* __restrict__ xv,
    const float* __restrict__ Wq, const float* __restrict__ Wk,
    const float* __restrict__ Wv, const float* __restrict__ Wo,
    const float* __restrict__ W1, const float* __restrict__ W2,
    __bf16* __restrict__ WqkvT, __bf16* __restrict__ WoT,
    __bf16* __restrict__ W1T, __bf16* __restrict__ W2T) {
  __shared__ float tl[32][33];
  if (blockIdx.x < 4096) {                    // ---- prep part
    int i = blockIdx.x * 256 + threadIdx.x;   // float4 group
    float4 pv = ((const float4*)pos)[i];
    float4 qv = ((const float4*)q)[i];
    float4 kv = ((const float4*)k)[i];
    float4 vv = ((const float4*)v)[i];
    ushort4 o;
    o.x = bfb(qv.x + pv.x); o.y = bfb(qv.y + pv.y); o.z = bfb(qv.z + pv.z); o.w = bfb(qv.w + pv.w);
    ((ushort4*)xq)[i] = o;
    o.x = bfb(kv.x + pv.x); o.y = bfb(kv.y + pv.y); o.z = bfb(kv.z + pv.z); o.w = bfb(kv.w + pv.w);
    ((ushort4*)xk)[i] = o;
    o.x = bfb(vv.x); o.y = bfb(vv.y); o.z = bfb(vv.z); o.w = bfb(vv.w);
    ((ushort4*)xv)[i] = o;
    return;
  }
  int idx = blockIdx.x - 4096;                // ---- weight transpose part
  const float* src; __bf16* dst; int K, N, t;
  if (idx < 768) {
    src = idx < 256 ? Wq : (idx < 512 ? Wk : Wv);
    dst = WqkvT + (size_t)(idx >> 8) * 512 * 512;
    K = 512; N = 512; t = idx & 255;
  } else if (idx < 1024) { src = Wo; dst = WoT;  K = 512;  N = 512;  t = idx - 768; }
  else if (idx < 2048)   { src = W1; dst = W1T;  K = 512;  N = 2048; t = idx - 1024; }
  else                   { src = W2; dst = W2T;  K = 2048; N = 512;  t = idx - 2048; }
  int tiles_n = N >> 5;
  int tn = t & (tiles_n - 1), tk = t / tiles_n;
  int n0 = tn * 32, k0 = tk * 32;
  int x = threadIdx.x & 31, y4 = threadIdx.x >> 5;
  #pragma unroll
  for (int j = y4; j < 32; j += 8) tl[j][x] = src[(size_t)(k0 + j) * N + n0 + x];
  __syncthreads();
  #pragma unroll
  for (int j = y4; j < 32; j += 8)
    dst[(size_t)(n0 + j) * K + k0 + x] = (__bf16)tl[x][j];
}

// ---------------- GEMM: C[M,N] = A[M,K] @ BT[N,K]^T + bias ------------------
// 2-phase pipelined: double-buffered LDS, counted vmcnt, raw barriers.
// EPI: 0 bf16 store, 1 bf16 relu store, 2 f32 store, 3 bf16 store + V-section
//      written transposed to Vtp (QKV gemm only).
template <int EPI, int BN>
__global__ __launch_bounds__(256, 2) void gemm_bt(
    const __bf16* __restrict__ A0, const __bf16* __restrict__ A1, const __bf16* __restrict__ A2,
    const __bf16* __restrict__ BT,
    const float* __restrict__ bias0, const float* __restrict__ bias1, const float* __restrict__ bias2,
    void* __restrict__ Cp, __bf16* __restrict__ Vtp, int M, int N, int K, int nsplit) {
  constexpr int NFR = BN / 32;          // B frags per wave
  constexpr int WCW = BN / 2;           // wave col width
  constexpr int BI  = BN / 32;          // B staging instrs per thread
  __shared__ __align__(16) __bf16 As[2][128 * 64];
  __shared__ __align__(16) __bf16 Bs[2][BN * 64];
  int tid = threadIdx.x, lane = tid & 63;
  int wave = tid >> 6;
  int wr = (wave >> 1) * 64, wc = (wave & 1) * WCW;

  int gx = N / BN;
  int nwg = gridDim.x;
  int cpx = nwg >> 3;
  int swz = (blockIdx.x & 7) * cpx + (blockIdx.x >> 3);
  int bx = swz % gx, by = swz / gx;
  int row0 = by << 7, col0 = bx * BN;

  int asel = col0 / nsplit;
  const __bf16* A = asel == 0 ? A0 : (asel == 1 ? A1 : A2);
  const float* bias = asel == 0 ? bias0 : (asel == 1 ? bias1 : bias2);

  f32x4 acc[4][NFR] = {};

#define GSTAGE(BUF, KT)                                                        \
  { _Pragma("unroll")                                                          \
    for (int i = 0; i < 4; ++i) {                                              \
      int t = i * 256 + tid;                                                   \
      int r = t >> 3, cS = (t & 7) ^ (r & 7);                                  \
      gld_lds16(A + (size_t)(row0 + r) * K + (KT) + cS * 8, As[BUF] + t * 8);  \
    }                                                                          \
    _Pragma("unroll")                                                          \
    for (int i = 0; i < BI; ++i) {                                             \
      int t = i * 256 + tid;                                                   \
      int r = t >> 3, cS = (t & 7) ^ (r & 7);                                  \
      gld_lds16(BT + (size_t)(col0 + r) * K + (KT) + cS * 8, Bs[BUF] + t * 8); \
    } }

#define GCOMP(BUF)                                                             \
  { const __bf16* Asc = As[BUF];                                               \
    const __bf16* Bsc = Bs[BUF];                                               \
    _Pragma("unroll")                                                          \
    for (int ks = 0; ks < 2; ++ks) {                                           \
      bf16x8 af[4], bfr[NFR];                                                  \
      _Pragma("unroll")                                                        \
      for (int m = 0; m < 4; ++m) {                                            \
        int r = wr + m * 16 + (lane & 15);                                     \
        int c = (ks * 4 + (lane >> 4)) ^ (r & 7);                              \
        af[m] = *(const bf16x8*)(Asc + r * 64 + c * 8);                        \
      }                                                                        \
      _Pragma("unroll")                                                        \
      for (int n = 0; n < NFR; ++n) {                                          \
        int r = wc + n * 16 + (lane & 15);                                     \
        int c = (ks * 4 + (lane >> 4)) ^ (r & 7);                              \
        bfr[n] = *(const bf16x8*)(Bsc + r * 64 + c * 8);                       \
      }                                                                        \
      _Pragma("unroll")                                                        \
      for (int m = 0; m < 4; ++m)                                              \
        _Pragma("unroll")                                                      \
        for (int n = 0; n < NFR; ++n)                                          \
          acc[m][n] = __builtin_amdgcn_mfma_f32_16x16x32_bf16(af[m], bfr[n], acc[m][n], 0, 0, 0); \
    } }

  GSTAGE(0, 0)
  int cur = 0;
  for (int kt = 64; kt < K; kt += 64) {
    GSTAGE(cur ^ 1, kt)
    if constexpr (BN == 128) asm volatile("s_waitcnt vmcnt(8)" ::: "memory");
    else                     asm volatile("s_waitcnt vmcnt(6)" ::: "memory");
    __builtin_amdgcn_s_barrier();
    __builtin_amdgcn_sched_barrier(0);
    GCOMP(cur)
    __builtin_amdgcn_s_barrier();     // protect buf[cur] from next stage
    cur ^= 1;
  }
  asm volatile("s_waitcnt vmcnt(0)" ::: "memory");
  __builtin_amdgcn_s_barrier();
  __builtin_amdgcn_sched_barrier(0);
  GCOMP(cur)
#undef GSTAGE
#undef GCOMP

  // epilogue: C row = (lane>>4)*4 + j, col = lane&15  (m89-verified layout)
  int rb = row0 + wr + ((lane >> 4) << 2);
  int cb = col0 + wc + (lane & 15);
  if (EPI == 3 && asel == 2) {
    // V panel: write transposed into Vt[(b*8+h)*64+d][n], packed 4 rows (8B)
    int bb = row0 >> 10;
    #pragma unroll
    for (int n = 0; n < NFR; ++n) {
      int c = cb + n * 16;                    // global col in [1024,1536)
      int d = c & 63, hh = (c >> 6) & 7;
      float bv = bias[c % nsplit];
      size_t vbase = ((size_t)((bb * 8 + hh) * 64 + d)) << 10;
      #pragma unroll
      for (int m = 0; m < 4; ++m) {
        int r0 = (rb + m * 16) & 1023;
        ushort4 pk;
        pk.x = bfb(acc[m][n][0] + bv);
        pk.y = bfb(acc[m][n][1] + bv);
        pk.z = bfb(acc[m][n][2] + bv);
        pk.w = bfb(acc[m][n][3] + bv);
        *(ushort4*)((__bf16*)Vtp + vbase + r0) = pk;
      }
    }
    return;
  }
  #pragma unroll
  for (int n = 0; n < NFR; ++n) {
    int c = cb + n * 16;
    float bv = bias[c % nsplit];
    #pragma unroll
    for (int m = 0; m < 4; ++m) {
      #pragma unroll
      for (int j = 0; j < 4; ++j) {
        int r = rb + m * 16 + j;
        float v = acc[m][n][j] + bv;
        if (EPI == 1) v = fmaxf(v, 0.f);
        if (EPI == 2) ((float*)Cp)[(size_t)r * N + c] = v;
        else          ((__bf16*)Cp)[(size_t)r * N + c] = (__bf16)v;
      }
    }
  }
}

// ---------------- fused attention v12: coalesced rgw + distance-2 pipeline ---
// The untested 2x2 cell: COALESCED rgw (gld_lds16, 8x128B lines/instr) AND
// counted-vmcnt pipelining. Ws triple-buffered at distance-2 (stage Ws(t+2)
// each phase); KV dbuf at distance-1 issued BEFORE Ws -> steady-state
// vmcnt(4) drains exactly {Ws(t), KV(t)}, Ws(t+1) stays in flight. LDS = 80KB
// exactly (Ks2 16 + Vs2 16 + Ws3 48) -> 2 blocks/CU, grid 1024 = 2 rounds:
//   - Q staged into Ws[2]'s slot (dead after phase-0 qf reads + syncthreads)
//   - P written into the wave's own quarter of the just-consumed Ws(t%3)
//     (per-wave-disjoint rows; next reuse of that buffer is barrier-protected)
// Ws swizzle/read math identical to R10 (absmax-verified). setprio (T5),
// XCD swizzle (T1).
__global__ __launch_bounds__(256, 2) void attn_kernel(
    const __bf16* __restrict__ QKV, const __bf16* __restrict__ Vt,
    const float* __restrict__ rgw, __bf16* __restrict__ O) {
  __shared__ __align__(16) __bf16 Ks[2][64 * 64];      // 16KB
  __shared__ __align__(16) __bf16 Vs[2][64 * 64];      // 16KB
  __shared__ __align__(16) float  Ws[3][64 * 64];      // 48KB

  int tid = threadIdx.x, lane = tid & 63, wave = tid >> 6;
  int flat = (blockIdx.x & 7) * 128 + (blockIdx.x >> 3);   // bijective XCD swz
  int qt = flat & 15, h = (flat >> 4) & 7, b = flat >> 7;
  int q0 = qt * 64;
  const int g = lane >> 4, u = lane & 15;
  const int wrow = wave * 16 + u;

  size_t wbase = ((size_t)(b * H_ + h) * N_ + (size_t)q0) * N_;  // rgw tile

#define STAGE_KV(BUF, KT)                                                      \
  {                                                                            \
    _Pragma("unroll")                                                          \
    for (int i = 0; i < 2; ++i) {                                              \
      int t = i * 256 + tid;                                                   \
      int r = t >> 3, cS = (t & 7) ^ (r & 7);                                  \
      gld_lds16(QKV + (size_t)(b * N_ + (KT) + r) * QKV_LD + DM + h * 64 + cS * 8, Ks[BUF] + t * 8); \
      gld_lds16(Vt + (size_t)((b * H_ + h) * 64 + r) * N_ + (KT) + cS * 8, Vs[BUF] + t * 8);         \
    }                                                                          \
  }
// stage 64x64 f32 rgw tile, chunk-XOR swizzle inverse-on-source (R10-verified)
#define STAGE_W(BUF3, KT)                                                      \
  {                                                                            \
    _Pragma("unroll")                                                          \
    for (int i = 0; i < 4; ++i) {                                              \
      int C = i * 256 + tid;          /* 16B chunk 0..1023 */                  \
      int R = C >> 4, c = C & 15;                                              \
      int sc = (c ^ (R & 7)) << 2;                                             \
      gld_lds16(rgw + wbase + (size_t)R * N_ + (KT) + sc, Ws[BUF3] + C * 4);   \
    }                                                                          \
  }

  // ---- prologue: Q -> Ws[2] slot; KV(0); Ws(0); then Ws(1) (stays in flight)
  {
    __bf16* QsA = (__bf16*)Ws[2];
    #pragma unroll
    for (int i = 0; i < 2; ++i) {
      int t = i * 256 + tid;
      int r = t >> 3, cS = (t & 7) ^ (r & 7);
      gld_lds16(QKV + (size_t)(b * N_ + q0 + r) * QKV_LD + h * 64 + cS * 8, QsA + t * 8);
    }
  }
  STAGE_KV(0, 0)
  STAGE_W(0, 0)
  __builtin_amdgcn_sched_barrier(0);
  STAGE_W(1, 64)
  __builtin_amdgcn_sched_barrier(0);

  float l = 0.f;
  f32x4 oacc[4] = {};
  bf16x8 qf[2];
  union Pk { __bf16 h4[4]; unsigned long long q; };

#define PHASE(T16, WAITSTR, DOKV, DOW)                                         \
  {                                                                            \
    asm volatile(WAITSTR ::: "memory");                                        \
    __builtin_amdgcn_s_barrier();                                              \
    if ((T16) == 0) {                                                          \
      const __bf16* QsA = (const __bf16*)Ws[2];                                \
      _Pragma("unroll")                                                        \
      for (int ks = 0; ks < 2; ++ks) {                                         \
        int c = (ks * 4 + g) ^ (wrow & 7);                                     \
        qf[ks] = *(const bf16x8*)(QsA + wrow * 64 + c * 8);                    \
      }                                                                        \
      __syncthreads();   /* all waves read Q before Ws(2) staging lands */     \
    }                                                                          \
    if (DOKV) { STAGE_KV(((T16) + 1) & 1, ((T16) + 1) * 64) }                  \
    __builtin_amdgcn_sched_barrier(0);                                         \
    if (DOW) { STAGE_W(((T16) + 2) % 3, ((T16) + 2) * 64) }                    \
    __builtin_amdgcn_sched_barrier(0);                                         \
    f32x4 s[4] = {};                                                           \
    __builtin_amdgcn_s_setprio(1);                                             \
    _Pragma("unroll")                                                          \
    for (int ks = 0; ks < 2; ++ks) {                                           \
      _Pragma("unroll")                                                        \
      for (int n = 0; n < 4; ++n) {                                            \
        int r = n * 16 + u;                                                    \
        int c = (ks * 4 + g) ^ (r & 7);                                        \
        bf16x8 kf = *(const bf16x8*)(Ks[(T16) & 1] + r * 64 + c * 8);          \
        s[n] = __builtin_amdgcn_mfma_f32_16x16x32_bf16(kf, qf[ks], s[n], 0, 0, 0); \
      }                                                                        \
    }                                                                          \
    __builtin_amdgcn_s_setprio(0);                                             \
    /* rgw from LDS: 4x ds_read_b128 (chunk-XOR), then P into the wave's own  */ \
    /* quarter of the SAME (consumed) Ws buffer                                */ \
    float* wsb = Ws[(T16) % 3];                                                \
    f32x4 w[4];                                                                \
    _Pragma("unroll")                                                          \
    for (int n = 0; n < 4; ++n)                                                \
      w[n] = *(const f32x4*)(wsb + wrow * 64 + (((4 * n + g) ^ (u & 7)) << 2)); \
    __builtin_amdgcn_sched_barrier(0);  /* w[] reads before P writes (alias) */ \
    __bf16* pw = (__bf16*)(wsb + wave * 16 * 64);                              \
    _Pragma("unroll")                                                          \
    for (int n = 0; n < 4; ++n) {                                              \
      Pk pk;                                                                   \
      _Pragma("unroll")                                                        \
      for (int j = 0; j < 4; ++j) {                                            \
        float pv = fmaxf(w[n][j], 1e-6f) * exp2f(s[n][j] * SCL);               \
        l += pv;                                                               \
        pk.h4[j] = (__bf16)pv;                                                 \
      }                                                                        \
      int bcol = 2 * n + (g >> 1);                                             \
      *(unsigned long long*)(pw + u * 64 + ((bcol ^ (u & 7)) << 3) + ((g & 1) << 2)) = pk.q; \
    }                                                                          \
    __builtin_amdgcn_s_setprio(1);                                             \
    _Pragma("unroll")                                                          \
    for (int ks = 0; ks < 2; ++ks) {                                           \
      int cp = (ks * 4 + g) ^ (u & 7);                                         \
      bf16x8 pa = *(const bf16x8*)(pw + u * 64 + cp * 8);                      \
      _Pragma("unroll")                                                        \
      for (int n = 0; n < 4; ++n) {                                            \
        int r = n * 16 + u;                                                    \
        int c = (ks * 4 + g) ^ (r & 7);                                        \
        bf16x8 vb = *(const bf16x8*)(Vs[(T16) & 1] + r * 64 + c * 8);          \
        oacc[n] = __builtin_amdgcn_mfma_f32_16x16x32_bf16(pa, vb, oacc[n], 0, 0, 0); \
      }                                                                        \
    }                                                                          \
    __builtin_amdgcn_s_setprio(0);                                             \
  }

  // Ledger (instrs/wave): prologue leaves [Q:2+KV0:4+Ws0:4 | Ws1:4].
  // top-0: vmcnt(4). Phase t issues KV(t+1):4 then Ws(t+2):4; steady top:
  // queue = [Ws(t):4, KV(t):4, Ws(t+1):4] -> vmcnt(4). top-15: vmcnt(0).
  PHASE(0,  "s_waitcnt vmcnt(4)", 1, 1)
  PHASE(1,  "s_waitcnt vmcnt(4)", 1, 1)
  PHASE(2,  "s_waitcnt vmcnt(4)", 1, 1)
  PHASE(3,  "s_waitcnt vmcnt(4)", 1, 1)
  PHASE(4,  "s_waitcnt vmcnt(4)", 1, 1)
  PHASE(5,  "s_waitcnt vmcnt(4)", 1, 1)
  PHASE(6,  "s_waitcnt vmcnt(4)", 1, 1)
  PHASE(7,  "s_waitcnt vmcnt(4)", 1, 1)
  PHASE(8,  "s_waitcnt vmcnt(4)", 1, 1)
  PHASE(9,  "s_waitcnt vmcnt(4)", 1, 1)
  PHASE(10, "s_waitcnt vmcnt(4)", 1, 1)
  PHASE(11, "s_waitcnt vmcnt(4)", 1, 1)
  PHASE(12, "s_waitcnt vmcnt(4)", 1, 1)
  PHASE(13, "s_waitcnt vmcnt(4)", 1, 1)
  PHASE(14, "s_waitcnt vmcnt(4)", 1, 0)
  PHASE(15, "s_waitcnt vmcnt(0)", 0, 0)
#undef PHASE
#undef STAGE_KV
#undef STAGE_W

  // row-sum: partials per lane (row u); sum across the 4 g-groups
  l += __shfl_xor(l, 16);
  l += __shfl_xor(l, 32);
  float linv[4];
  #pragma unroll
  for (int j = 0; j < 4; ++j)
    linv[j] = 1.f / __shfl(l, (lane & 48) | (g * 4 + j));

  int orow = b * N_ + q0 + wave * 16 + g * 4;
  int ocol = h * 64 + u;
  #pragma unroll
  for (int j = 0; j < 4; ++j)
    #pragma unroll
    for (int n = 0; n < 4; ++n)
      O[(size_t)(orow + j) * DM + ocol + n * 16] = (__bf16)(oacc[n][j] * linv[j]);
}

// ---------------- LayerNorm(x1 + x2); x2 optionally bf16 --------------------
template <int WRITE_BF, int X2BF>
__global__ __launch_bounds__(256) void ln_kernel(
    const float* __restrict__ x1, const void* __restrict__ x2v,
    const float* __restrict__ gw, const float* __restrict__ bw,
    float* __restrict__ outf, __bf16* __restrict__ outb) {
  __shared__ float red[8];
  int row = blockIdx.x, t = threadIdx.x;
  size_t base = (size_t)row * DM;
  float2 a = ((const float2*)(x1 + base))[t];
  float b0, b1;
  if (X2BF) {
    unsigned p = ((const unsigned*)x2v)[base / 2 + t];
    union { unsigned u; float f; } c0, c1;
    c0.u = p << 16; c1.u = p & 0xffff0000u;
    b0 = c0.f; b1 = c1.f;
  } else {
    float2 bb = ((const float2*)x2v)[base / 2 + t];
    b0 = bb.x; b1 = bb.y;
  }
  float v0 = a.x + b0, v1 = a.y + b1;
  float s = v0 + v1, s2 = v0 * v0 + v1 * v1;
  #pragma unroll
  for (int o = 32; o; o >>= 1) { s += __shfl_xor(s, o); s2 += __shfl_xor(s2, o); }
  int wave = t >> 6;
  if ((t & 63) == 0) { red[wave] = s; red[4 + wave] = s2; }
  __syncthreads();
  s = red[0] + red[1] + red[2] + red[3];
  s2 = red[4] + red[5] + red[6] + red[7];
  float mu = s * (1.f / DM);
  float var = s2 * (1.f / DM) - mu * mu;
  float rstd = rsqrtf(var + 1e-5f);
  float y0 = (v0 - mu) * rstd * gw[2 * t] + bw[2 * t];
  float y1 = (v1 - mu) * rstd * gw[2 * t + 1] + bw[2 * t + 1];
  float2 r; r.x = y0; r.y = y1;
  ((float2*)(outf + base))[t] = r;
  if (WRITE_BF) {
    ushort2 h; h.x = bfb(y0); h.y = bfb(y1);
    ((ushort2*)(outb + base))[t] = h;
  }
}

// ---------------- launch -----------------------------------------------------
extern "C" void kernel_launch(void* const* d_in, const int* in_sizes, int n_in,
                              void* d_out, int out_size, void* d_ws, size_t ws_size,
                              hipStream_t stream) {
  const float* queries = (const float*)d_in[0];
  const float* keys    = (const float*)d_in[1];
  const float* values  = (const float*)d_in[2];
  const float* rgw     = (const float*)d_in[3];
  const float* pos     = (const float*)d_in[4];
  const float* Wq = (const float*)d_in[5];
  const float* bq = (const float*)d_in[6];
  const float* Wk = (const float*)d_in[7];
  const float* bk = (const float*)d_in[8];
  const float* Wv = (const float*)d_in[9];
  const float* bv = (const float*)d_in[10];
  const float* Wo = (const float*)d_in[11];
  const float* bo = (const float*)d_in[12];
  const float* ln1g = (const float*)d_in[13];
  const float* ln1b = (const float*)d_in[14];
  const float* W1 = (const float*)d_in[15];
  const float* b1 = (const float*)d_in[16];
  const float* W2 = (const float*)d_in[17];
  const float* b2 = (const float*)d_in[18];
  const float* ln2g = (const float*)d_in[19];
  const float* ln2b = (const float*)d_in[20];
  float* out = (float*)d_out;

  char* ws = (char*)d_ws;
  const size_t SZX = (size_t)ROWS * DM * 2;        // 8 MB (bf16 8192x512)
  __bf16* Xq    = (__bf16*)(ws);
  __bf16* Xk    = (__bf16*)(ws + SZX);
  __bf16* Xv    = (__bf16*)(ws + 2 * SZX);
  __bf16* WqkvT = (__bf16*)(ws + 3 * SZX);                       // 1536x512
  __bf16* WoT   = (__bf16*)(ws + 3 * SZX + 1572864);             // 512x512
  __bf16* W1T   = (__bf16*)(ws + 3 * SZX + 2097152);             // 2048x512
  __bf16* W2T   = (__bf16*)(ws + 3 * SZX + 4194304);             // 512x2048
  __bf16* QKV   = (__bf16*)(ws + 3 * SZX + 6291456);             // 8192x1536
  __bf16* Vt    = (__bf16*)(ws + 3 * SZX + 6291456 + 3 * SZX);   // (B,H,64,N)
  __bf16* Oat   = (__bf16*)(ws + 3 * SZX + 6291456 + 4 * SZX);
  // aliases over dead regions:
  __bf16* attprojb = Xq;            // bf16 8192x512 over Xq (dead after QKV)
  __bf16* attoutb  = Xv;            // over Xv (dead after QKV GEMM)
  float*  attoutf  = (float*)QKV;   // f32 over QKV (dead after attention)
  __bf16* ff2b     = Vt;            // bf16 over Vt (dead after attention)
  __bf16* ff1      = (__bf16*)(ws + 3 * SZX + 6291456 + 5 * SZX); // 8192x2048

  prep_and_wt<<<4096 + 3072, 256, 0, stream>>>(
      queries, keys, values, pos, Xq, Xk, Xv,
      Wq, Wk, Wv, Wo, W1, W2, WqkvT, WoT, W1T, W2T);

  // QKV: C[8192,1536]; V panel goes straight to Vt (transposed)
  gemm_bt<3, 128><<<(ROWS / 128) * (QKV_LD / 128), 256, 0, stream>>>(
      Xq, Xk, Xv, WqkvT, bq, bk, bv, QKV, Vt, ROWS, QKV_LD, DM, DM);

  attn_kernel<<<B_ * H_ * (N_ / 64), 256, 0, stream>>>(QKV, Vt, rgw, Oat);

  // Wo -> bf16 attprojb; LN1(queries + attprojb) -> f32 + bf16
  gemm_bt<0, 64><<<(ROWS / 128) * (DM / 64), 256, 0, stream>>>(
      Oat, Oat, Oat, WoT, bo, bo, bo, attprojb, nullptr, ROWS, DM, DM, DM);

  ln_kernel<1, 1><<<ROWS, 256, 0, stream>>>(queries, attprojb, ln1g, ln1b, attoutf, attoutb);

  gemm_bt<1, 128><<<(ROWS / 128) * (DFF / 128), 256, 0, stream>>>(
      attoutb, attoutb, attoutb, W1T, b1, b1, b1, ff1, nullptr, ROWS, DFF, DM, DFF);

  // FF2 -> bf16 ff2b; LN2(attoutf + ff2b) -> out
  gemm_bt<0, 64><<<(ROWS / 128) * (DM / 64), 256, 0, stream>>>(
      ff1, ff1, ff1, W2T, b2, b2, b2, ff2b, nullptr, ROWS, DM, DFF, DM);

  ln_kernel<0, 1><<<ROWS, 256, 0, stream>>>(attoutf, ff2b, ln2g, ln2b, out, nullptr);
}

// Round 16
// 209.486 us; speedup vs baseline: 1.2262x; 1.0760x over previous
//
#include <hip/hip_runtime.h>
#include <hip/hip_bf16.h>
#include <stdint.h>

// EncoderLayer: B=8 N=1024 D=512 H=8 Dh=64 FF=2048
#define B_   8
#define N_   1024
#define DM   512
#define H_   8
#define DFF  2048
#define ROWS (B_ * N_)          // 8192
#define QKV_LD (3 * DM)         // 1536
#define LOG2E 1.4426950408889634f
#define SCL  (0.125f * LOG2E)   // att scale 1/8 folded into exp2

typedef __bf16 bf16x8 __attribute__((ext_vector_type(8)));
typedef float  f32x4  __attribute__((ext_vector_type(4)));

__device__ __forceinline__ void gld_lds16(const void* g, void* l) {
  __builtin_amdgcn_global_load_lds((__attribute__((address_space(1))) void*)g,
                                   (__attribute__((address_space(3))) void*)l, 16, 0, 0);
}

__device__ __forceinline__ unsigned short bfb(float x) {
  __bf16 h = (__bf16)x;
  unsigned short u;
  __builtin_memcpy(&u, &h, 2);
  return u;
}

// ------- fused: prep (x_q=q+pos etc -> bf16) + all weight transposes --------
__global__ __launch_bounds__(256) void prep_and_wt(
    const float* __restrict__ q, const float* __restrict__ k,
    const float* __restrict__ v, const float* __restrict__ pos,
    __bf16* __restrict__ xq, __bf16* __restrict__ xk, __bf16* __restrict__ xv,
    const float* __restrict__ Wq, const float* __restrict__ Wk,
    const float* __restrict__ Wv, const float* __restrict__ Wo,
    const float* __restrict__ W1, const float* __restrict__ W2,
    __bf16* __restrict__ WqkvT, __bf16* __restrict__ WoT,
    __bf16* __restrict__ W1T, __bf16* __restrict__ W2T) {
  __shared__ float tl[32][33];
  if (blockIdx.x < 4096) {                    // ---- prep part
    int i = blockIdx.x * 256 + threadIdx.x;   // float4 group
    float4 pv = ((const float4*)pos)[i];
    float4 qv = ((const float4*)q)[i];
    float4 kv = ((const float4*)k)[i];
    float4 vv = ((const float4*)v)[i];
    ushort4 o;
    o.x = bfb(qv.x + pv.x); o.y = bfb(qv.y + pv.y); o.z = bfb(qv.z + pv.z); o.w = bfb(qv.w + pv.w);
    ((ushort4*)xq)[i] = o;
    o.x = bfb(kv.x + pv.x); o.y = bfb(kv.y + pv.y); o.z = bfb(kv.z + pv.z); o.w = bfb(kv.w + pv.w);
    ((ushort4*)xk)[i] = o;
    o.x = bfb(vv.x); o.y = bfb(vv.y); o.z = bfb(vv.z); o.w = bfb(vv.w);
    ((ushort4*)xv)[i] = o;
    return;
  }
  int idx = blockIdx.x - 4096;                // ---- weight transpose part
  const float* src; __bf16* dst; int K, N, t;
  if (idx < 768) {
    src = idx < 256 ? Wq : (idx < 512 ? Wk : Wv);
    dst = WqkvT + (size_t)(idx >> 8) * 512 * 512;
    K = 512; N = 512; t = idx & 255;
  } else if (idx < 1024) { src = Wo; dst = WoT;  K = 512;  N = 512;  t = idx - 768; }
  else if (idx < 2048)   { src = W1; dst = W1T;  K = 512;  N = 2048; t = idx - 1024; }
  else                   { src = W2; dst = W2T;  K = 2048; N = 512;  t = idx - 2048; }
  int tiles_n = N >> 5;
  int tn = t & (tiles_n - 1), tk = t / tiles_n;
  int n0 = tn * 32, k0 = tk * 32;
  int x = threadIdx.x & 31, y4 = threadIdx.x >> 5;
  #pragma unroll
  for (int j = y4; j < 32; j += 8) tl[j][x] = src[(size_t)(k0 + j) * N + n0 + x];
  __syncthreads();
  #pragma unroll
  for (int j = y4; j < 32; j += 8)
    dst[(size_t)(n0 + j) * K + k0 + x] = (__bf16)tl[x][j];
}

// ---------------- GEMM: C[M,N] = A[M,K] @ BT[N,K]^T + bias ------------------
// 2-phase pipelined: double-buffered LDS, counted vmcnt, raw barriers.
// EPI: 0 bf16 store, 1 bf16 relu store, 2 f32 store, 3 bf16 store + V-section
//      written transposed to Vtp (QKV gemm only).
template <int EPI, int BN>
__global__ __launch_bounds__(256, 2) void gemm_bt(
    const __bf16* __restrict__ A0, const __bf16* __restrict__ A1, const __bf16* __restrict__ A2,
    const __bf16* __restrict__ BT,
    const float* __restrict__ bias0, const float* __restrict__ bias1, const float* __restrict__ bias2,
    void* __restrict__ Cp, __bf16* __restrict__ Vtp, int M, int N, int K, int nsplit) {
  constexpr int NFR = BN / 32;          // B frags per wave
  constexpr int WCW = BN / 2;           // wave col width
  constexpr int BI  = BN / 32;          // B staging instrs per thread
  __shared__ __align__(16) __bf16 As[2][128 * 64];
  __shared__ __align__(16) __bf16 Bs[2][BN * 64];
  int tid = threadIdx.x, lane = tid & 63;
  int wave = tid >> 6;
  int wr = (wave >> 1) * 64, wc = (wave & 1) * WCW;

  int gx = N / BN;
  int nwg = gridDim.x;
  int cpx = nwg >> 3;
  int swz = (blockIdx.x & 7) * cpx + (blockIdx.x >> 3);
  int bx = swz % gx, by = swz / gx;
  int row0 = by << 7, col0 = bx * BN;

  int asel = col0 / nsplit;
  const __bf16* A = asel == 0 ? A0 : (asel == 1 ? A1 : A2);
  const float* bias = asel == 0 ? bias0 : (asel == 1 ? bias1 : bias2);

  f32x4 acc[4][NFR] = {};

#define GSTAGE(BUF, KT)                                                        \
  { _Pragma("unroll")                                                          \
    for (int i = 0; i < 4; ++i) {                                              \
      int t = i * 256 + tid;                                                   \
      int r = t >> 3, cS = (t & 7) ^ (r & 7);                                  \
      gld_lds16(A + (size_t)(row0 + r) * K + (KT) + cS * 8, As[BUF] + t * 8);  \
    }                                                                          \
    _Pragma("unroll")                                                          \
    for (int i = 0; i < BI; ++i) {                                             \
      int t = i * 256 + tid;                                                   \
      int r = t >> 3, cS = (t & 7) ^ (r & 7);                                  \
      gld_lds16(BT + (size_t)(col0 + r) * K + (KT) + cS * 8, Bs[BUF] + t * 8); \
    } }

#define GCOMP(BUF)                                                             \
  { const __bf16* Asc = As[BUF];                                               \
    const __bf16* Bsc = Bs[BUF];                                               \
    _Pragma("unroll")                                                          \
    for (int ks = 0; ks < 2; ++ks) {                                           \
      bf16x8 af[4], bfr[NFR];                                                  \
      _Pragma("unroll")                                                        \
      for (int m = 0; m < 4; ++m) {                                            \
        int r = wr + m * 16 + (lane & 15);                                     \
        int c = (ks * 4 + (lane >> 4)) ^ (r & 7);                              \
        af[m] = *(const bf16x8*)(Asc + r * 64 + c * 8);                        \
      }                                                                        \
      _Pragma("unroll")                                                        \
      for (int n = 0; n < NFR; ++n) {                                          \
        int r = wc + n * 16 + (lane & 15);                                     \
        int c = (ks * 4 + (lane >> 4)) ^ (r & 7);                              \
        bfr[n] = *(const bf16x8*)(Bsc + r * 64 + c * 8);                       \
      }                                                                        \
      _Pragma("unroll")                                                        \
      for (int m = 0; m < 4; ++m)                                              \
        _Pragma("unroll")                                                      \
        for (int n = 0; n < NFR; ++n)                                          \
          acc[m][n] = __builtin_amdgcn_mfma_f32_16x16x32_bf16(af[m], bfr[n], acc[m][n], 0, 0, 0); \
    } }

  GSTAGE(0, 0)
  int cur = 0;
  for (int kt = 64; kt < K; kt += 64) {
    GSTAGE(cur ^ 1, kt)
    if constexpr (BN == 128) asm volatile("s_waitcnt vmcnt(8)" ::: "memory");
    else                     asm volatile("s_waitcnt vmcnt(6)" ::: "memory");
    __builtin_amdgcn_s_barrier();
    __builtin_amdgcn_sched_barrier(0);
    GCOMP(cur)
    __builtin_amdgcn_s_barrier();     // protect buf[cur] from next stage
    cur ^= 1;
  }
  asm volatile("s_waitcnt vmcnt(0)" ::: "memory");
  __builtin_amdgcn_s_barrier();
  __builtin_amdgcn_sched_barrier(0);
  GCOMP(cur)
#undef GSTAGE
#undef GCOMP

  // epilogue: C row = (lane>>4)*4 + j, col = lane&15  (m89-verified layout)
  int rb = row0 + wr + ((lane >> 4) << 2);
  int cb = col0 + wc + (lane & 15);
  if (EPI == 3 && asel == 2) {
    // V panel: write transposed into Vt[(b*8+h)*64+d][n], packed 4 rows (8B)
    int bb = row0 >> 10;
    #pragma unroll
    for (int n = 0; n < NFR; ++n) {
      int c = cb + n * 16;                    // global col in [1024,1536)
      int d = c & 63, hh = (c >> 6) & 7;
      float bv = bias[c % nsplit];
      size_t vbase = ((size_t)((bb * 8 + hh) * 64 + d)) << 10;
      #pragma unroll
      for (int m = 0; m < 4; ++m) {
        int r0 = (rb + m * 16) & 1023;
        ushort4 pk;
        pk.x = bfb(acc[m][n][0] + bv);
        pk.y = bfb(acc[m][n][1] + bv);
        pk.z = bfb(acc[m][n][2] + bv);
        pk.w = bfb(acc[m][n][3] + bv);
        *(ushort4*)((__bf16*)Vtp + vbase + r0) = pk;
      }
    }
    return;
  }
  #pragma unroll
  for (int n = 0; n < NFR; ++n) {
    int c = cb + n * 16;
    float bv = bias[c % nsplit];
    #pragma unroll
    for (int m = 0; m < 4; ++m) {
      #pragma unroll
      for (int j = 0; j < 4; ++j) {
        int r = rb + m * 16 + j;
        float v = acc[m][n][j] + bv;
        if (EPI == 1) v = fmaxf(v, 0.f);
        if (EPI == 2) ((float*)Cp)[(size_t)r * N + c] = v;
        else          ((__bf16*)Cp)[(size_t)r * N + c] = (__bf16)v;
      }
    }
  }
}

// ---------------- fused attention v9 (R12-verbatim, measured best) -----------
// softmax(log(clip(w)) + s) == normalize(clip(w) * exp(s)) exactly.
// SWAPPED QK^T: mfma(K,Q) -> lane owns q-row u, att-cols n*16+g*4+{0..3}.
// 1 q-tile blocks with Qs ALIASED over Ps (Q is register-cached in phase 0,
// Qs dead after; one extra barrier after phase-0 QK protects the alias) ->
// LDS 40KB -> 4 blocks/CU, grid 1024 = EXACTLY 4/CU, no tail. rgw: 2-deep
// register prefetch (dwordx4), KV dbuf, counted vmcnt(4) (T3/T4), setprio
// (T5), XCD swizzle (T1).
__global__ __launch_bounds__(256, 4) void attn_kernel(
    const __bf16* __restrict__ QKV, const __bf16* __restrict__ Vt,
    const float* __restrict__ rgw, __bf16* __restrict__ O) {
  __shared__ __align__(16) __bf16 QsPs[64 * 64];       // Qs (phase0) ∪ Ps
  __shared__ __align__(16) __bf16 Ks[2][64 * 64];
  __shared__ __align__(16) __bf16 Vs[2][64 * 64];

  int tid = threadIdx.x, lane = tid & 63, wave = tid >> 6;
  int flat = (blockIdx.x & 7) * 128 + (blockIdx.x >> 3);   // bijective XCD swz
  int qt = flat & 15, h = (flat >> 4) & 7, b = flat >> 7;
  int q0 = qt * 64;
  const int g = lane >> 4, u = lane & 15;

  // lane's q-row = q0 + wave*16 + u; att-col chunk starts at g*4
  const float* rgw_p = rgw +
      ((size_t)(b * H_ + h) * N_ + (size_t)(q0 + wave * 16 + u)) * N_ + g * 4;

#define STAGE_KV(BUF, KT)                                                      \
  {                                                                            \
    _Pragma("unroll")                                                          \
    for (int i = 0; i < 2; ++i) {                                              \
      int t = i * 256 + tid;                                                   \
      int r = t >> 3, cS = (t & 7) ^ (r & 7);                                  \
      gld_lds16(QKV + (size_t)(b * N_ + (KT) + r) * QKV_LD + DM + h * 64 + cS * 8, Ks[BUF] + t * 8); \
      gld_lds16(Vt + (size_t)((b * H_ + h) * 64 + r) * N_ + (KT) + cS * 8, Vs[BUF] + t * 8);         \
    }                                                                          \
  }
#define RPF(W, T)                                                              \
  {                                                                            \
    _Pragma("unroll")                                                          \
    for (int n = 0; n < 4; ++n)                                                \
      W[n] = __builtin_nontemporal_load((const f32x4*)(rgw_p + (size_t)(T) * 64 + n * 16)); \
  }

  // ---- prologue: Q + KV[0] -> LDS; rgw tiles 0,1 -> registers ----
  #pragma unroll
  for (int i = 0; i < 2; ++i) {
    int t = i * 256 + tid;
    int r = t >> 3, cS = (t & 7) ^ (r & 7);
    gld_lds16(QKV + (size_t)(b * N_ + q0 + r) * QKV_LD + h * 64 + cS * 8, QsPs + t * 8);
  }
  STAGE_KV(0, 0)
  __builtin_amdgcn_sched_barrier(0);   // rgw loads AFTER Q/KV in the queue
  f32x4 wA[4], wB[4];
  RPF(wA, 0) RPF(wB, 1)
  __builtin_amdgcn_sched_barrier(0);

  float l = 0.f;
  f32x4 oacc[4] = {};
  bf16x8 qf[2];
  __bf16* pw = &QsPs[wave * 16 * 64];
  const int wrow = wave * 16 + u;
  union Pk { __bf16 h4[4]; unsigned long long q; };

#define PHASE(T16, WAITSTR, DOSTAGE, DORPF, WCON)                              \
  {                                                                            \
    asm volatile(WAITSTR ::: "memory");                                        \
    __builtin_amdgcn_s_barrier();                                              \
    if (DOSTAGE) { STAGE_KV(((T16) + 1) & 1, ((T16) + 1) * 64) }               \
    __builtin_amdgcn_sched_barrier(0);                                         \
    if ((T16) == 0) {                                                          \
      _Pragma("unroll")                                                        \
      for (int ks = 0; ks < 2; ++ks) {                                         \
        int c = (ks * 4 + g) ^ (wrow & 7);                                     \
        qf[ks] = *(const bf16x8*)(QsPs + wrow * 64 + c * 8);                   \
      }                                                                        \
    }                                                                          \
    f32x4 s[4] = {};                                                           \
    __builtin_amdgcn_s_setprio(1);                                             \
    _Pragma("unroll")                                                          \
    for (int ks = 0; ks < 2; ++ks) {                                           \
      _Pragma("unroll")                                                        \
      for (int n = 0; n < 4; ++n) {                                            \
        int r = n * 16 + u;                                                    \
        int c = (ks * 4 + g) ^ (r & 7);                                        \
        bf16x8 kf = *(const bf16x8*)(Ks[(T16) & 1] + r * 64 + c * 8);          \
        s[n] = __builtin_amdgcn_mfma_f32_16x16x32_bf16(kf, qf[ks], s[n], 0, 0, 0); \
      }                                                                        \
    }                                                                          \
    __builtin_amdgcn_s_setprio(0);                                             \
    if ((T16) == 0) __builtin_amdgcn_s_barrier();  /* all qf reads done before Ps writes (alias) */ \
    _Pragma("unroll")                                                          \
    for (int n = 0; n < 4; ++n) {                                              \
      Pk pk;                                                                   \
      _Pragma("unroll")                                                        \
      for (int j = 0; j < 4; ++j) {                                            \
        float pv = fmaxf(WCON[n][j], 1e-6f) * exp2f(s[n][j] * SCL);            \
        l += pv;                                                               \
        pk.h4[j] = (__bf16)pv;                                                 \
      }                                                                        \
      int bcol = 2 * n + (g >> 1);                                             \
      *(unsigned long long*)(pw + u * 64 + ((bcol ^ (u & 7)) << 3) + ((g & 1) << 2)) = pk.q; \
    }                                                                          \
    __builtin_amdgcn_sched_barrier(0);                                         \
    if (DORPF) { RPF(WCON, (T16) + 2) }                                        \
    __builtin_amdgcn_sched_barrier(0);                                         \
    __builtin_amdgcn_s_setprio(1);                                             \
    _Pragma("unroll")                                                          \
    for (int ks = 0; ks < 2; ++ks) {                                           \
      int cp = (ks * 4 + g) ^ (u & 7);                                         \
      bf16x8 pa = *(const bf16x8*)(pw + u * 64 + cp * 8);                      \
      _Pragma("unroll")                                                        \
      for (int n = 0; n < 4; ++n) {                                            \
        int r = n * 16 + u;                                                    \
        int c = (ks * 4 + g) ^ (r & 7);                                        \
        bf16x8 vb = *(const bf16x8*)(Vs[(T16) & 1] + r * 64 + c * 8);          \
        oacc[n] = __builtin_amdgcn_mfma_f32_16x16x32_bf16(pa, vb, oacc[n], 0, 0, 0); \
      }                                                                        \
    }                                                                          \
    __builtin_amdgcn_s_setprio(0);                                             \
  }

  PHASE(0,  "s_waitcnt vmcnt(8)", 1, 1, wA)
  PHASE(1,  "s_waitcnt vmcnt(4)", 1, 1, wB)
  PHASE(2,  "s_waitcnt vmcnt(4)", 1, 1, wA)
  PHASE(3,  "s_waitcnt vmcnt(4)", 1, 1, wB)
  PHASE(4,  "s_waitcnt vmcnt(4)", 1, 1, wA)
  PHASE(5,  "s_waitcnt vmcnt(4)", 1, 1, wB)
  PHASE(6,  "s_waitcnt vmcnt(4)", 1, 1, wA)
  PHASE(7,  "s_waitcnt vmcnt(4)", 1, 1, wB)
  PHASE(8,  "s_waitcnt vmcnt(4)", 1, 1, wA)
  PHASE(9,  "s_waitcnt vmcnt(4)", 1, 1, wB)
  PHASE(10, "s_waitcnt vmcnt(4)", 1, 1, wA)
  PHASE(11, "s_waitcnt vmcnt(4)", 1, 1, wB)
  PHASE(12, "s_waitcnt vmcnt(4)", 1, 1, wA)
  PHASE(13, "s_waitcnt vmcnt(4)", 1, 1, wB)
  PHASE(14, "s_waitcnt vmcnt(4)", 1, 0, wA)
  PHASE(15, "s_waitcnt vmcnt(0)", 0, 0, wB)
#undef PHASE
#undef STAGE_KV
#undef RPF

  // row-sum: partials per lane (row u); sum across the 4 g-groups
  l += __shfl_xor(l, 16);
  l += __shfl_xor(l, 32);
  float linv[4];
  #pragma unroll
  for (int j = 0; j < 4; ++j)
    linv[j] = 1.f / __shfl(l, (lane & 48) | (g * 4 + j));

  int orow = b * N_ + q0 + wave * 16 + g * 4;
  int ocol = h * 64 + u;
  #pragma unroll
  for (int j = 0; j < 4; ++j)
    #pragma unroll
    for (int n = 0; n < 4; ++n)
      O[(size_t)(orow + j) * DM + ocol + n * 16] = (__bf16)(oacc[n][j] * linv[j]);
}

// ---------------- LayerNorm(x1 + x2); x2 optionally bf16 --------------------
template <int WRITE_BF, int X2BF>
__global__ __launch_bounds__(256) void ln_kernel(
    const float* __restrict__ x1, const void* __restrict__ x2v,
    const float* __restrict__ gw, const float* __restrict__ bw,
    float* __restrict__ outf, __bf16* __restrict__ outb) {
  __shared__ float red[8];
  int row = blockIdx.x, t = threadIdx.x;
  size_t base = (size_t)row * DM;
  float2 a = ((const float2*)(x1 + base))[t];
  float b0, b1;
  if (X2BF) {
    unsigned p = ((const unsigned*)x2v)[base / 2 + t];
    union { unsigned u; float f; } c0, c1;
    c0.u = p << 16; c1.u = p & 0xffff0000u;
    b0 = c0.f; b1 = c1.f;
  } else {
    float2 bb = ((const float2*)x2v)[base / 2 + t];
    b0 = bb.x; b1 = bb.y;
  }
  float v0 = a.x + b0, v1 = a.y + b1;
  float s = v0 + v1, s2 = v0 * v0 + v1 * v1;
  #pragma unroll
  for (int o = 32; o; o >>= 1) { s += __shfl_xor(s, o); s2 += __shfl_xor(s2, o); }
  int wave = t >> 6;
  if ((t & 63) == 0) { red[wave] = s; red[4 + wave] = s2; }
  __syncthreads();
  s = red[0] + red[1] + red[2] + red[3];
  s2 = red[4] + red[5] + red[6] + red[7];
  float mu = s * (1.f / DM);
  float var = s2 * (1.f / DM) - mu * mu;
  float rstd = rsqrtf(var + 1e-5f);
  float y0 = (v0 - mu) * rstd * gw[2 * t] + bw[2 * t];
  float y1 = (v1 - mu) * rstd * gw[2 * t + 1] + bw[2 * t + 1];
  float2 r; r.x = y0; r.y = y1;
  ((float2*)(outf + base))[t] = r;
  if (WRITE_BF) {
    ushort2 h; h.x = bfb(y0); h.y = bfb(y1);
    ((ushort2*)(outb + base))[t] = h;
  }
}

// ---------------- launch -----------------------------------------------------
extern "C" void kernel_launch(void* const* d_in, const int* in_sizes, int n_in,
                              void* d_out, int out_size, void* d_ws, size_t ws_size,
                              hipStream_t stream) {
  const float* queries = (const float*)d_in[0];
  const float* keys    = (const float*)d_in[1];
  const float* values  = (const float*)d_in[2];
  const float* rgw     = (const float*)d_in[3];
  const float* pos     = (const float*)d_in[4];
  const float* Wq = (const float*)d_in[5];
  const float* bq = (const float*)d_in[6];
  const float* Wk = (const float*)d_in[7];
  const float* bk = (const float*)d_in[8];
  const float* Wv = (const float*)d_in[9];
  const float* bv = (const float*)d_in[10];
  const float* Wo = (const float*)d_in[11];
  const float* bo = (const float*)d_in[12];
  const float* ln1g = (const float*)d_in[13];
  const float* ln1b = (const float*)d_in[14];
  const float* W1 = (const float*)d_in[15];
  const float* b1 = (const float*)d_in[16];
  const float* W2 = (const float*)d_in[17];
  const float* b2 = (const float*)d_in[18];
  const float* ln2g = (const float*)d_in[19];
  const float* ln2b = (const float*)d_in[20];
  float* out = (float*)d_out;

  char* ws = (char*)d_ws;
  const size_t SZX = (size_t)ROWS * DM * 2;        // 8 MB (bf16 8192x512)
  __bf16* Xq    = (__bf16*)(ws);
  __bf16* Xk    = (__bf16*)(ws + SZX);
  __bf16* Xv    = (__bf16*)(ws + 2 * SZX);
  __bf16* WqkvT = (__bf16*)(ws + 3 * SZX);                       // 1536x512
  __bf16* WoT   = (__bf16*)(ws + 3 * SZX + 1572864);             // 512x512
  __bf16* W1T   = (__bf16*)(ws + 3 * SZX + 2097152);             // 2048x512
  __bf16* W2T   = (__bf16*)(ws + 3 * SZX + 4194304);             // 512x2048
  __bf16* QKV   = (__bf16*)(ws + 3 * SZX + 6291456);             // 8192x1536
  __bf16* Vt    = (__bf16*)(ws + 3 * SZX + 6291456 + 3 * SZX);   // (B,H,64,N)
  __bf16* Oat   = (__bf16*)(ws + 3 * SZX + 6291456 + 4 * SZX);
  // aliases over dead regions:
  __bf16* attprojb = Xq;            // bf16 8192x512 over Xq (dead after QKV)
  __bf16* attoutb  = Xv;            // over Xv (dead after QKV GEMM)
  float*  attoutf  = (float*)QKV;   // f32 over QKV (dead after attention)
  __bf16* ff2b     = Vt;            // bf16 over Vt (dead after attention)
  __bf16* ff1      = (__bf16*)(ws + 3 * SZX + 6291456 + 5 * SZX); // 8192x2048

  prep_and_wt<<<4096 + 3072, 256, 0, stream>>>(
      queries, keys, values, pos, Xq, Xk, Xv,
      Wq, Wk, Wv, Wo, W1, W2, WqkvT, WoT, W1T, W2T);

  // QKV: C[8192,1536]; V panel goes straight to Vt (transposed)
  gemm_bt<3, 128><<<(ROWS / 128) * (QKV_LD / 128), 256, 0, stream>>>(
      Xq, Xk, Xv, WqkvT, bq, bk, bv, QKV, Vt, ROWS, QKV_LD, DM, DM);

  attn_kernel<<<B_ * H_ * (N_ / 64), 256, 0, stream>>>(QKV, Vt, rgw, Oat);

  // Wo -> bf16 attprojb; LN1(queries + attprojb) -> f32 + bf16
  gemm_bt<0, 64><<<(ROWS / 128) * (DM / 64), 256, 0, stream>>>(
      Oat, Oat, Oat, WoT, bo, bo, bo, attprojb, nullptr, ROWS, DM, DM, DM);

  ln_kernel<1, 1><<<ROWS, 256, 0, stream>>>(queries, attprojb, ln1g, ln1b, attoutf, attoutb);

  gemm_bt<1, 128><<<(ROWS / 128) * (DFF / 128), 256, 0, stream>>>(
      attoutb, attoutb, attoutb, W1T, b1, b1, b1, ff1, nullptr, ROWS, DFF, DM, DFF);

  // FF2 -> bf16 ff2b; LN2(attoutf + ff2b) -> out
  gemm_bt<0, 64><<<(ROWS / 128) * (DM / 64), 256, 0, stream>>>(
      ff1, ff1, ff1, W2T, b2, b2, b2, ff2b, nullptr, ROWS, DM, DFF, DM);

  ln_kernel<0, 1><<<ROWS, 256, 0, stream>>>(attoutf, ff2b, ln2g, ln2b, out, nullptr);
}